// Round 1
// baseline (482.620 us; speedup 1.0000x reference)
//
#include <hip/hip_runtime.h>
#include <hip/hip_bf16.h>

typedef __attribute__((ext_vector_type(8))) short short8;
typedef __attribute__((ext_vector_type(4))) float f32x4;
typedef __attribute__((ext_vector_type(4))) unsigned short ushort4v;
typedef unsigned short ushort;

#define DEVI static __device__ __forceinline__

// ---------- bf16 helpers (RNE) ----------
DEVI ushort f2bf(float f){
  union { float f; unsigned u; } v; v.f = f;
  unsigned r = v.u + 0x7fffu + ((v.u >> 16) & 1u);
  return (ushort)(r >> 16);
}
DEVI float bf2f(ushort u){
  union { unsigned u; float f; } v; v.u = ((unsigned)u) << 16;
  return v.f;
}

// ---------- async global->LDS (16B per lane, linear dest) ----------
DEVI void gload_lds16(const void* g, void* l){
  __builtin_amdgcn_global_load_lds(
      (const __attribute__((address_space(1))) void*)g,
      (__attribute__((address_space(3))) void*)l, 16, 0, 0);
}

// =====================================================================
// P1: cast fp32 -> bf16 (vectorized)
// =====================================================================
__global__ __launch_bounds__(256) void cast_bf16(const float4* __restrict__ in,
                                                 ushort* __restrict__ out, int n4){
  int i = blockIdx.x * 256 + threadIdx.x;
  if (i < n4){
    float4 v = in[i];
    ushort4v o = { f2bf(v.x), f2bf(v.y), f2bf(v.z), f2bf(v.w) };
    *(ushort4v*)&out[(size_t)i * 4] = o;
  }
}

// =====================================================================
// P2: transpose + cast fp32[R][C] -> bf16[C][R] (optional hi/lo split)
// =====================================================================
template<int SPLIT>
__global__ __launch_bounds__(256) void transpose_cast(const float* __restrict__ in,
                                                      ushort* __restrict__ outT,
                                                      ushort* __restrict__ outLo,
                                                      int R, int C){
  __shared__ float tile[64][65];
  const int r0 = blockIdx.y * 64, c0 = blockIdx.x * 64;
  const int t = threadIdx.x;
  for (int it = 0; it < 16; ++it){
    int idx = it * 256 + t; int rr = idx >> 6, cc = idx & 63;
    tile[rr][cc] = in[(size_t)(r0 + rr) * C + (c0 + cc)];
  }
  __syncthreads();
  for (int it = 0; it < 16; ++it){
    int idx = it * 256 + t; int oc = idx >> 6, orow = idx & 63;
    float v = tile[orow][oc];
    ushort hi = f2bf(v);
    size_t o = (size_t)(c0 + oc) * R + (r0 + orow);
    outT[o] = hi;
    if (SPLIT) outLo[o] = f2bf(v - bf2f(hi));
  }
}

// =====================================================================
// G1: QKV projection.  C[8192,3072] = xb[8192,1024] @ wqkvT^T + b_qkv
// writes Q/K/V as bf16 in [B*H, T, 64] layout
// =====================================================================
__global__ __launch_bounds__(256) void gemm_qkv(const ushort* __restrict__ A,
                                                const ushort* __restrict__ BT,
                                                const float* __restrict__ bias,
                                                ushort* __restrict__ Qo,
                                                ushort* __restrict__ Ko,
                                                ushort* __restrict__ Vo){
  constexpr int K = 1024;
  __shared__ __align__(16) ushort As[128 * 32];
  __shared__ __align__(16) ushort Bs[128 * 32];
  const int tid = threadIdx.x, w = tid >> 6, l = tid & 63;
  const int wr = w >> 1, wc = w & 1;
  const int mtile = blockIdx.y * 128, ntile = blockIdx.x * 128;

  f32x4 acc[4][4];
  for (int m = 0; m < 4; ++m) for (int n = 0; n < 4; ++n)
    for (int r = 0; r < 4; ++r) acc[m][n][r] = 0.f;

  const int c0 = 2 * w, c1 = 2 * w + 1;
  const ushort* aG0 = A  + (size_t)(mtile + c0 * 16 + (l >> 2)) * K + (l & 3) * 8;
  const ushort* aG1 = A  + (size_t)(mtile + c1 * 16 + (l >> 2)) * K + (l & 3) * 8;
  const ushort* bG0 = BT + (size_t)(ntile + c0 * 16 + (l >> 2)) * K + (l & 3) * 8;
  const ushort* bG1 = BT + (size_t)(ntile + c1 * 16 + (l >> 2)) * K + (l & 3) * 8;

  for (int kt = 0; kt < K / 32; ++kt){
    __syncthreads();
    gload_lds16(aG0 + kt * 32, &As[c0 * 512]);
    gload_lds16(aG1 + kt * 32, &As[c1 * 512]);
    gload_lds16(bG0 + kt * 32, &Bs[c0 * 512]);
    gload_lds16(bG1 + kt * 32, &Bs[c1 * 512]);
    __syncthreads();
    short8 aF[4], bF[4];
    for (int m = 0; m < 4; ++m)
      aF[m] = *(const short8*)&As[(wr * 64 + m * 16 + (l & 15)) * 32 + (l >> 4) * 8];
    for (int n = 0; n < 4; ++n)
      bF[n] = *(const short8*)&Bs[(wc * 64 + n * 16 + (l & 15)) * 32 + (l >> 4) * 8];
    for (int m = 0; m < 4; ++m)
      for (int n = 0; n < 4; ++n)
        acc[m][n] = __builtin_amdgcn_mfma_f32_16x16x32_bf16(aF[m], bF[n], acc[m][n], 0, 0, 0);
  }

  for (int nf = 0; nf < 4; ++nf){
    int ncol = ntile + wc * 64 + nf * 16 + (l & 15);
    float bv = bias[ncol];
    int which = ncol >> 10, h = (ncol >> 6) & 15, d = ncol & 63;
    ushort* dst = (which == 0) ? Qo : ((which == 1) ? Ko : Vo);
    for (int m = 0; m < 4; ++m){
      int rbase = mtile + wr * 64 + m * 16 + (l >> 4) * 4;
      for (int r = 0; r < 4; ++r){
        int row = rbase + r;
        int b = row >> 11, t = row & 2047;
        dst[((size_t)(b * 16 + h) * 2048 + t) * 64 + d] = f2bf(acc[m][nf][r] + bv);
      }
    }
  }
}

// =====================================================================
// A: flash attention, one block = 64 q-rows of one (b,h); 4 waves x 16 rows
// =====================================================================
__global__ __launch_bounds__(256) void attn_fwd(const ushort* __restrict__ Q,
                                                const ushort* __restrict__ Kb,
                                                const ushort* __restrict__ Vb,
                                                ushort* __restrict__ Ohi,
                                                ushort* __restrict__ Olo){
  __shared__ __align__(16) ushort Ks[64 * 64];     // [key][d] linear (global_load_lds)
  __shared__ __align__(16) ushort Vt[64][72];      // [d][key], padded
  __shared__ __align__(16) ushort Ps[4][16][72];   // per-wave P, padded
  const int tid = threadIdx.x, w = tid >> 6, l = tid & 63;
  const int bh = blockIdx.y, qbase = blockIdx.x * 64;
  const ushort* Qp = Q  + (size_t)bh * 2048 * 64;
  const ushort* Kp = Kb + (size_t)bh * 2048 * 64;
  const ushort* Vp = Vb + (size_t)bh * 2048 * 64;

  const int qrow = qbase + w * 16 + (l & 15);
  short8 qf0 = *(const short8*)&Qp[(size_t)qrow * 64 + (l >> 4) * 8];
  short8 qf1 = *(const short8*)&Qp[(size_t)qrow * 64 + 32 + (l >> 4) * 8];

  float mrow[4], lrow[4];
  f32x4 oacc[4];
  for (int r = 0; r < 4; ++r){ mrow[r] = -1e30f; lrow[r] = 0.f; }
  for (int c = 0; c < 4; ++c) for (int r = 0; r < 4; ++r) oacc[c][r] = 0.f;

  const int vkey = tid & 63, vd = (tid >> 6) * 8;
  const int c0 = 2 * w, c1 = 2 * w + 1;

  for (int kt = 0; kt < 32; ++kt){
    const int kb = kt * 64;
    __syncthreads();                               // prev-iter LDS reads done
    gload_lds16(Kp + (size_t)(kb + c0 * 8 + (l >> 3)) * 64 + (l & 7) * 8, &Ks[c0 * 512]);
    gload_lds16(Kp + (size_t)(kb + c1 * 8 + (l >> 3)) * 64 + (l & 7) * 8, &Ks[c1 * 512]);
    short8 v0 = *(const short8*)&Vp[(size_t)(kb + vkey) * 64 + vd];
    short8 v1 = *(const short8*)&Vp[(size_t)(kb + vkey) * 64 + vd + 32];
    for (int j = 0; j < 8; ++j){
      Vt[vd + j][vkey]      = (ushort)v0[j];
      Vt[vd + 32 + j][vkey] = (ushort)v1[j];
    }
    __syncthreads();                               // K + Vt staged

    f32x4 s[4];
    for (int nf = 0; nf < 4; ++nf) for (int r = 0; r < 4; ++r) s[nf][r] = 0.f;
    for (int nf = 0; nf < 4; ++nf){
      short8 kf0 = *(const short8*)&Ks[(nf * 16 + (l & 15)) * 64 + (l >> 4) * 8];
      short8 kf1 = *(const short8*)&Ks[(nf * 16 + (l & 15)) * 64 + 32 + (l >> 4) * 8];
      s[nf] = __builtin_amdgcn_mfma_f32_16x16x32_bf16(qf0, kf0, s[nf], 0, 0, 0);
      s[nf] = __builtin_amdgcn_mfma_f32_16x16x32_bf16(qf1, kf1, s[nf], 0, 0, 0);
    }

    float pmax[4];
    for (int r = 0; r < 4; ++r) pmax[r] = -1e30f;
    for (int nf = 0; nf < 4; ++nf)
      for (int r = 0; r < 4; ++r){
        float sv = s[nf][r] * 0.125f; s[nf][r] = sv;
        pmax[r] = fmaxf(pmax[r], sv);
      }
    for (int off = 1; off < 16; off <<= 1)
      for (int r = 0; r < 4; ++r) pmax[r] = fmaxf(pmax[r], __shfl_xor(pmax[r], off));

    float alpha[4], rsum[4];
    for (int r = 0; r < 4; ++r){
      float mn = fmaxf(mrow[r], pmax[r]);
      alpha[r] = __expf(mrow[r] - mn);
      mrow[r] = mn; rsum[r] = 0.f;
    }
    for (int nf = 0; nf < 4; ++nf)
      for (int r = 0; r < 4; ++r){
        float p = __expf(s[nf][r] - mrow[r]);
        s[nf][r] = p; rsum[r] += p;
      }
    for (int nf = 0; nf < 4; ++nf)
      for (int r = 0; r < 4; ++r)
        Ps[w][(l >> 4) * 4 + r][nf * 16 + (l & 15)] = f2bf(s[nf][r]);
    for (int off = 1; off < 16; off <<= 1)
      for (int r = 0; r < 4; ++r) rsum[r] += __shfl_xor(rsum[r], off);
    for (int r = 0; r < 4; ++r) lrow[r] = lrow[r] * alpha[r] + rsum[r];
    for (int c = 0; c < 4; ++c)
      for (int r = 0; r < 4; ++r) oacc[c][r] *= alpha[r];
    __syncthreads();                               // P visible (cross-lane)

    for (int st = 0; st < 2; ++st){
      short8 pf = *(const short8*)&Ps[w][(l & 15)][st * 32 + (l >> 4) * 8];
      for (int c = 0; c < 4; ++c){
        short8 vf = *(const short8*)&Vt[c * 16 + (l & 15)][st * 32 + (l >> 4) * 8];
        oacc[c] = __builtin_amdgcn_mfma_f32_16x16x32_bf16(pf, vf, oacc[c], 0, 0, 0);
      }
    }
  }

  const int b = bh >> 4, h = bh & 15;
  for (int r = 0; r < 4; ++r){
    float inv = 1.0f / lrow[r];
    int q = qbase + w * 16 + (l >> 4) * 4 + r;
    size_t rowoff = ((size_t)(b * 2048 + q)) * 1024 + h * 64;
    for (int c = 0; c < 4; ++c){
      float val = oacc[c][r] * inv;
      ushort hi = f2bf(val);
      Ohi[rowoff + c * 16 + (l & 15)] = hi;
      Olo[rowoff + c * 16 + (l & 15)] = f2bf(val - bf2f(hi));
    }
  }
}

// =====================================================================
// G2: output projection with bf16 hi/lo split (3 MFMAs per product)
// =====================================================================
__global__ __launch_bounds__(256) void gemm_out(const ushort* __restrict__ Ah,
                                                const ushort* __restrict__ Al,
                                                const ushort* __restrict__ BhT,
                                                const ushort* __restrict__ BlT,
                                                const float* __restrict__ bias,
                                                float* __restrict__ out){
  constexpr int K = 1024;
  __shared__ __align__(16) ushort Ash[128 * 32], Asl[128 * 32];
  __shared__ __align__(16) ushort Bsh[128 * 32], Bsl[128 * 32];
  const int tid = threadIdx.x, w = tid >> 6, l = tid & 63;
  const int wr = w >> 1, wc = w & 1;
  const int mtile = blockIdx.y * 128, ntile = blockIdx.x * 128;

  f32x4 acc[4][4];
  for (int m = 0; m < 4; ++m) for (int n = 0; n < 4; ++n)
    for (int r = 0; r < 4; ++r) acc[m][n][r] = 0.f;

  const int c0 = 2 * w, c1 = 2 * w + 1;
  const size_t aOff0 = (size_t)(mtile + c0 * 16 + (l >> 2)) * K + (l & 3) * 8;
  const size_t aOff1 = (size_t)(mtile + c1 * 16 + (l >> 2)) * K + (l & 3) * 8;
  const size_t bOff0 = (size_t)(ntile + c0 * 16 + (l >> 2)) * K + (l & 3) * 8;
  const size_t bOff1 = (size_t)(ntile + c1 * 16 + (l >> 2)) * K + (l & 3) * 8;

  for (int kt = 0; kt < K / 32; ++kt){
    __syncthreads();
    gload_lds16(Ah  + aOff0 + kt * 32, &Ash[c0 * 512]);
    gload_lds16(Ah  + aOff1 + kt * 32, &Ash[c1 * 512]);
    gload_lds16(Al  + aOff0 + kt * 32, &Asl[c0 * 512]);
    gload_lds16(Al  + aOff1 + kt * 32, &Asl[c1 * 512]);
    gload_lds16(BhT + bOff0 + kt * 32, &Bsh[c0 * 512]);
    gload_lds16(BhT + bOff1 + kt * 32, &Bsh[c1 * 512]);
    gload_lds16(BlT + bOff0 + kt * 32, &Bsl[c0 * 512]);
    gload_lds16(BlT + bOff1 + kt * 32, &Bsl[c1 * 512]);
    __syncthreads();
    short8 aH[4], aL[4], bH[4], bL[4];
    for (int m = 0; m < 4; ++m){
      int o = (wr * 64 + m * 16 + (l & 15)) * 32 + (l >> 4) * 8;
      aH[m] = *(const short8*)&Ash[o];
      aL[m] = *(const short8*)&Asl[o];
    }
    for (int n = 0; n < 4; ++n){
      int o = (wc * 64 + n * 16 + (l & 15)) * 32 + (l >> 4) * 8;
      bH[n] = *(const short8*)&Bsh[o];
      bL[n] = *(const short8*)&Bsl[o];
    }
    for (int m = 0; m < 4; ++m)
      for (int n = 0; n < 4; ++n){
        acc[m][n] = __builtin_amdgcn_mfma_f32_16x16x32_bf16(aH[m], bH[n], acc[m][n], 0, 0, 0);
        acc[m][n] = __builtin_amdgcn_mfma_f32_16x16x32_bf16(aH[m], bL[n], acc[m][n], 0, 0, 0);
        acc[m][n] = __builtin_amdgcn_mfma_f32_16x16x32_bf16(aL[m], bH[n], acc[m][n], 0, 0, 0);
      }
  }

  for (int nf = 0; nf < 4; ++nf){
    int ncol = ntile + wc * 64 + nf * 16 + (l & 15);
    float bv = bias[ncol];
    for (int m = 0; m < 4; ++m){
      int rbase = mtile + wr * 64 + m * 16 + (l >> 4) * 4;
      for (int r = 0; r < 4; ++r)
        out[(size_t)(rbase + r) * 1024 + ncol] = acc[m][nf][r] + bv;
    }
  }
}

// =====================================================================
extern "C" void kernel_launch(void* const* d_in, const int* in_sizes, int n_in,
                              void* d_out, int out_size, void* d_ws, size_t ws_size,
                              hipStream_t stream){
  const float* x     = (const float*)d_in[0];
  const float* w_qkv = (const float*)d_in[1];
  const float* b_qkv = (const float*)d_in[2];
  const float* w_out = (const float*)d_in[3];
  const float* b_out = (const float*)d_in[4];
  float* out = (float*)d_out;
  char* ws = (char*)d_ws;

  size_t off = 0;
  auto alloc = [&](size_t bytes){ size_t o = off; off += (bytes + 255) & ~(size_t)255; return o; };
  const size_t SZ_X   = (size_t)8192 * 1024 * 2;   // 16 MiB
  const size_t SZ_QKV = (size_t)64 * 2048 * 64 * 2;
  size_t o_xb  = alloc(SZ_X);                      // xb; reused as Ohi after G1
  size_t o_wq  = alloc((size_t)3072 * 1024 * 2);
  size_t o_q   = alloc(SZ_QKV);
  size_t o_k   = alloc(SZ_QKV);
  size_t o_v   = alloc(SZ_QKV);
  size_t o_olo = alloc(SZ_X);
  size_t o_wh  = alloc((size_t)1024 * 1024 * 2);
  size_t o_wl  = alloc((size_t)1024 * 1024 * 2);

  ushort* xb  = (ushort*)(ws + o_xb);
  ushort* wqT = (ushort*)(ws + o_wq);
  ushort* Qb  = (ushort*)(ws + o_q);
  ushort* Kb  = (ushort*)(ws + o_k);
  ushort* Vb  = (ushort*)(ws + o_v);
  ushort* Ohi = (ushort*)(ws + o_xb);              // alias: xb dead after G1
  ushort* Olo = (ushort*)(ws + o_olo);
  ushort* WhT = (ushort*)(ws + o_wh);
  ushort* WlT = (ushort*)(ws + o_wl);

  cast_bf16<<<8192, 256, 0, stream>>>((const float4*)x, xb, 8192 * 1024 / 4);
  transpose_cast<0><<<dim3(48, 16), 256, 0, stream>>>(w_qkv, wqT, nullptr, 1024, 3072);
  transpose_cast<1><<<dim3(16, 16), 256, 0, stream>>>(w_out, WhT, WlT, 1024, 1024);
  gemm_qkv<<<dim3(24, 64), 256, 0, stream>>>(xb, wqT, b_qkv, Qb, Kb, Vb);
  attn_fwd<<<dim3(32, 64), 256, 0, stream>>>(Qb, Kb, Vb, Ohi, Olo);
  gemm_out<<<dim3(8, 64), 256, 0, stream>>>(Ohi, Olo, WhT, WlT, b_out, out);
}

// Round 3
// 471.538 us; speedup vs baseline: 1.0235x; 1.0235x over previous
//
#include <hip/hip_runtime.h>
#include <hip/hip_bf16.h>

typedef __attribute__((ext_vector_type(8))) short short8;
typedef __attribute__((ext_vector_type(4))) float f32x4;
typedef __attribute__((ext_vector_type(4))) unsigned short ushort4v;
typedef unsigned short ushort;

#define DEVI static __device__ __forceinline__

// ---------- bf16 helpers (RNE) ----------
DEVI ushort f2bf(float f){
  union { float f; unsigned u; } v; v.f = f;
  unsigned r = v.u + 0x7fffu + ((v.u >> 16) & 1u);
  return (ushort)(r >> 16);
}
DEVI float bf2f(ushort u){
  union { unsigned u; float f; } v; v.u = ((unsigned)u) << 16;
  return v.f;
}

// ---------- async global->LDS (16B per lane, linear dest) ----------
DEVI void gload_lds16(const void* g, void* l){
  __builtin_amdgcn_global_load_lds(
      (const __attribute__((address_space(1))) void*)g,
      (__attribute__((address_space(3))) void*)l, 16, 0, 0);
}

// =====================================================================
// P1: cast fp32 -> bf16 (vectorized)
// =====================================================================
__global__ __launch_bounds__(256) void cast_bf16(const float4* __restrict__ in,
                                                 ushort* __restrict__ out, int n4){
  int i = blockIdx.x * 256 + threadIdx.x;
  if (i < n4){
    float4 v = in[i];
    ushort4v o = { f2bf(v.x), f2bf(v.y), f2bf(v.z), f2bf(v.w) };
    *(ushort4v*)&out[(size_t)i * 4] = o;
  }
}

// =====================================================================
// P2: transpose + cast fp32[R][C] -> bf16[C][R] (optional hi/lo split)
// =====================================================================
template<int SPLIT>
__global__ __launch_bounds__(256) void transpose_cast(const float* __restrict__ in,
                                                      ushort* __restrict__ outT,
                                                      ushort* __restrict__ outLo,
                                                      int R, int C){
  __shared__ float tile[64][65];
  const int r0 = blockIdx.y * 64, c0 = blockIdx.x * 64;
  const int t = threadIdx.x;
  for (int it = 0; it < 16; ++it){
    int idx = it * 256 + t; int rr = idx >> 6, cc = idx & 63;
    tile[rr][cc] = in[(size_t)(r0 + rr) * C + (c0 + cc)];
  }
  __syncthreads();
  for (int it = 0; it < 16; ++it){
    int idx = it * 256 + t; int oc = idx >> 6, orow = idx & 63;
    float v = tile[orow][oc];
    ushort hi = f2bf(v);
    size_t o = (size_t)(c0 + oc) * R + (r0 + orow);
    outT[o] = hi;
    if (SPLIT) outLo[o] = f2bf(v - bf2f(hi));
  }
}

// =====================================================================
// G1: QKV projection.  C[8192,3072] = xb[8192,1024] @ wqkvT^T + b_qkv
// writes Q/K/V as bf16 in [B*H, T, 64] layout
// =====================================================================
__global__ __launch_bounds__(256) void gemm_qkv(const ushort* __restrict__ A,
                                                const ushort* __restrict__ BT,
                                                const float* __restrict__ bias,
                                                ushort* __restrict__ Qo,
                                                ushort* __restrict__ Ko,
                                                ushort* __restrict__ Vo){
  constexpr int K = 1024;
  __shared__ __align__(16) ushort As[128 * 32];
  __shared__ __align__(16) ushort Bs[128 * 32];
  const int tid = threadIdx.x, w = tid >> 6, l = tid & 63;
  const int wr = w >> 1, wc = w & 1;
  const int mtile = blockIdx.y * 128, ntile = blockIdx.x * 128;

  f32x4 acc[4][4];
  for (int m = 0; m < 4; ++m) for (int n = 0; n < 4; ++n)
    for (int r = 0; r < 4; ++r) acc[m][n][r] = 0.f;

  const int c0 = 2 * w, c1 = 2 * w + 1;
  const ushort* aG0 = A  + (size_t)(mtile + c0 * 16 + (l >> 2)) * K + (l & 3) * 8;
  const ushort* aG1 = A  + (size_t)(mtile + c1 * 16 + (l >> 2)) * K + (l & 3) * 8;
  const ushort* bG0 = BT + (size_t)(ntile + c0 * 16 + (l >> 2)) * K + (l & 3) * 8;
  const ushort* bG1 = BT + (size_t)(ntile + c1 * 16 + (l >> 2)) * K + (l & 3) * 8;

  for (int kt = 0; kt < K / 32; ++kt){
    __syncthreads();
    gload_lds16(aG0 + kt * 32, &As[c0 * 512]);
    gload_lds16(aG1 + kt * 32, &As[c1 * 512]);
    gload_lds16(bG0 + kt * 32, &Bs[c0 * 512]);
    gload_lds16(bG1 + kt * 32, &Bs[c1 * 512]);
    __syncthreads();
    short8 aF[4], bF[4];
    for (int m = 0; m < 4; ++m)
      aF[m] = *(const short8*)&As[(wr * 64 + m * 16 + (l & 15)) * 32 + (l >> 4) * 8];
    for (int n = 0; n < 4; ++n)
      bF[n] = *(const short8*)&Bs[(wc * 64 + n * 16 + (l & 15)) * 32 + (l >> 4) * 8];
    for (int m = 0; m < 4; ++m)
      for (int n = 0; n < 4; ++n)
        acc[m][n] = __builtin_amdgcn_mfma_f32_16x16x32_bf16(aF[m], bF[n], acc[m][n], 0, 0, 0);
  }

  for (int nf = 0; nf < 4; ++nf){
    int ncol = ntile + wc * 64 + nf * 16 + (l & 15);
    float bv = bias[ncol];
    int which = ncol >> 10, h = (ncol >> 6) & 15, d = ncol & 63;
    ushort* dst = (which == 0) ? Qo : ((which == 1) ? Ko : Vo);
    for (int m = 0; m < 4; ++m){
      int rbase = mtile + wr * 64 + m * 16 + (l >> 4) * 4;
      for (int r = 0; r < 4; ++r){
        int row = rbase + r;
        int b = row >> 11, t = row & 2047;
        dst[((size_t)(b * 16 + h) * 2048 + t) * 64 + d] = f2bf(acc[m][nf][r] + bv);
      }
    }
  }
}

// =====================================================================
// A: flash attention, one block = 64 q-rows of one (b,h); 4 waves x 16 rows
// K tile XOR-swizzled (rule #21: linear LDS dest, inverse-swizzled global
// source, swizzled ds_read) -> conflict-free b128 K fragment reads.
// =====================================================================
__global__ __launch_bounds__(256) void attn_fwd(const ushort* __restrict__ Q,
                                                const ushort* __restrict__ Kb,
                                                const ushort* __restrict__ Vb,
                                                ushort* __restrict__ Ohi,
                                                ushort* __restrict__ Olo){
  __shared__ __align__(16) ushort Ks[64 * 64];     // [key][d] swizzled
  __shared__ __align__(16) ushort Vt[64][72];      // [d][key], padded
  __shared__ __align__(16) ushort Ps[4][16][72];   // per-wave P, padded
  const int tid = threadIdx.x, w = tid >> 6, l = tid & 63;
  const int bh = blockIdx.y, qbase = blockIdx.x * 64;
  const ushort* Qp = Q  + (size_t)bh * 2048 * 64;
  const ushort* Kp = Kb + (size_t)bh * 2048 * 64;
  const ushort* Vp = Vb + (size_t)bh * 2048 * 64;

  // log2-domain scale: exp(s/8) == 2^(s * 0.125*log2(e))
  constexpr float SCALE = 0.18033688011112042f;
  constexpr float DEFER_THR = 8.0f;                // 2^8 P-value headroom

  const int qrow = qbase + w * 16 + (l & 15);
  short8 qf0 = *(const short8*)&Qp[(size_t)qrow * 64 + (l >> 4) * 8];
  short8 qf1 = *(const short8*)&Qp[(size_t)qrow * 64 + 32 + (l >> 4) * 8];

  float mrow[4], lrow[4];
  f32x4 oacc[4];
  for (int r = 0; r < 4; ++r){ mrow[r] = -1e30f; lrow[r] = 0.f; }
  for (int c = 0; c < 4; ++c) for (int r = 0; r < 4; ++r) oacc[c][r] = 0.f;

  const int vkey = tid & 63, vd = (tid >> 6) * 8;
  const int c0 = 2 * w, c1 = 2 * w + 1;
  // inverse-swizzled K source column (16B units): (l&7) ^ (l>>3)
  const int ksrc = ((l & 7) ^ (l >> 3)) * 8;
  const int kr0 = c0 * 8 + (l >> 3), kr1 = c1 * 8 + (l >> 3);
  // swizzled read col offsets (ushort units)
  const int rrow = l & 15;                          // fragment row within 16
  const int rxor = (rrow & 7) * 8;

  for (int kt = 0; kt < 32; ++kt){
    const int kb = kt * 64;
    __syncthreads();                               // prev-iter LDS reads done
    gload_lds16(Kp + (size_t)(kb + kr0) * 64 + ksrc, &Ks[c0 * 512]);
    gload_lds16(Kp + (size_t)(kb + kr1) * 64 + ksrc, &Ks[c1 * 512]);
    short8 v0 = *(const short8*)&Vp[(size_t)(kb + vkey) * 64 + vd];
    short8 v1 = *(const short8*)&Vp[(size_t)(kb + vkey) * 64 + vd + 32];
    for (int j = 0; j < 8; ++j){
      Vt[vd + j][vkey]      = (ushort)v0[j];
      Vt[vd + 32 + j][vkey] = (ushort)v1[j];
    }
    __syncthreads();                               // K + Vt staged

    f32x4 s[4];
    for (int nf = 0; nf < 4; ++nf) for (int r = 0; r < 4; ++r) s[nf][r] = 0.f;
    __builtin_amdgcn_s_setprio(1);
    for (int nf = 0; nf < 4; ++nf){
      int rb = (nf * 16 + rrow) * 64;
      short8 kf0 = *(const short8*)&Ks[rb + (((l >> 4) * 8)      ^ rxor)];
      short8 kf1 = *(const short8*)&Ks[rb + (((l >> 4) * 8 + 32) ^ rxor)];
      s[nf] = __builtin_amdgcn_mfma_f32_16x16x32_bf16(qf0, kf0, s[nf], 0, 0, 0);
      s[nf] = __builtin_amdgcn_mfma_f32_16x16x32_bf16(qf1, kf1, s[nf], 0, 0, 0);
    }
    __builtin_amdgcn_s_setprio(0);

    float pmax[4];
    for (int r = 0; r < 4; ++r) pmax[r] = -1e30f;
    for (int nf = 0; nf < 4; ++nf)
      for (int r = 0; r < 4; ++r){
        float sv = s[nf][r] * SCALE; s[nf][r] = sv;
        pmax[r] = fmaxf(pmax[r], sv);
      }
    for (int off = 1; off < 16; off <<= 1)
      for (int r = 0; r < 4; ++r) pmax[r] = fmaxf(pmax[r], __shfl_xor(pmax[r], off));

    // defer-max: skip rescale when per-tile max growth is small (T13)
    bool defer = true;
    for (int r = 0; r < 4; ++r) defer = defer && (pmax[r] <= mrow[r] + DEFER_THR);
    if (!__all(defer)){
      for (int r = 0; r < 4; ++r){
        float mn = fmaxf(mrow[r], pmax[r]);
        float alpha = exp2f(mrow[r] - mn);
        mrow[r] = mn;
        lrow[r] *= alpha;
        for (int c = 0; c < 4; ++c) oacc[c][r] *= alpha;
      }
    }

    float rsum[4];
    for (int r = 0; r < 4; ++r) rsum[r] = 0.f;
    for (int nf = 0; nf < 4; ++nf)
      for (int r = 0; r < 4; ++r){
        float p = exp2f(s[nf][r] - mrow[r]);
        s[nf][r] = p; rsum[r] += p;
      }
    for (int nf = 0; nf < 4; ++nf)
      for (int r = 0; r < 4; ++r)
        Ps[w][(l >> 4) * 4 + r][nf * 16 + (l & 15)] = f2bf(s[nf][r]);
    for (int off = 1; off < 16; off <<= 1)
      for (int r = 0; r < 4; ++r) rsum[r] += __shfl_xor(rsum[r], off);
    for (int r = 0; r < 4; ++r) lrow[r] += rsum[r];
    // NOTE: no __syncthreads here — Ps is wave-private; compiler orders
    // the ds_write->ds_read with lgkmcnt.

    __builtin_amdgcn_s_setprio(1);
    for (int st = 0; st < 2; ++st){
      short8 pf = *(const short8*)&Ps[w][(l & 15)][st * 32 + (l >> 4) * 8];
      for (int c = 0; c < 4; ++c){
        short8 vf = *(const short8*)&Vt[c * 16 + (l & 15)][st * 32 + (l >> 4) * 8];
        oacc[c] = __builtin_amdgcn_mfma_f32_16x16x32_bf16(pf, vf, oacc[c], 0, 0, 0);
      }
    }
    __builtin_amdgcn_s_setprio(0);
  }

  const int b = bh >> 4, h = bh & 15;
  for (int r = 0; r < 4; ++r){
    float inv = 1.0f / lrow[r];
    int q = qbase + w * 16 + (l >> 4) * 4 + r;
    size_t rowoff = ((size_t)(b * 2048 + q)) * 1024 + h * 64;
    for (int c = 0; c < 4; ++c){
      float val = oacc[c][r] * inv;
      ushort hi = f2bf(val);
      Ohi[rowoff + c * 16 + (l & 15)] = hi;
      Olo[rowoff + c * 16 + (l & 15)] = f2bf(val - bf2f(hi));
    }
  }
}

// =====================================================================
// G2: output projection with bf16 hi/lo split (3 MFMAs per product)
// =====================================================================
__global__ __launch_bounds__(256) void gemm_out(const ushort* __restrict__ Ah,
                                                const ushort* __restrict__ Al,
                                                const ushort* __restrict__ BhT,
                                                const ushort* __restrict__ BlT,
                                                const float* __restrict__ bias,
                                                float* __restrict__ out){
  constexpr int K = 1024;
  __shared__ __align__(16) ushort Ash[128 * 32], Asl[128 * 32];
  __shared__ __align__(16) ushort Bsh[128 * 32], Bsl[128 * 32];
  const int tid = threadIdx.x, w = tid >> 6, l = tid & 63;
  const int wr = w >> 1, wc = w & 1;
  const int mtile = blockIdx.y * 128, ntile = blockIdx.x * 128;

  f32x4 acc[4][4];
  for (int m = 0; m < 4; ++m) for (int n = 0; n < 4; ++n)
    for (int r = 0; r < 4; ++r) acc[m][n][r] = 0.f;

  const int c0 = 2 * w, c1 = 2 * w + 1;
  const size_t aOff0 = (size_t)(mtile + c0 * 16 + (l >> 2)) * K + (l & 3) * 8;
  const size_t aOff1 = (size_t)(mtile + c1 * 16 + (l >> 2)) * K + (l & 3) * 8;
  const size_t bOff0 = (size_t)(ntile + c0 * 16 + (l >> 2)) * K + (l & 3) * 8;
  const size_t bOff1 = (size_t)(ntile + c1 * 16 + (l >> 2)) * K + (l & 3) * 8;

  for (int kt = 0; kt < K / 32; ++kt){
    __syncthreads();
    gload_lds16(Ah  + aOff0 + kt * 32, &Ash[c0 * 512]);
    gload_lds16(Ah  + aOff1 + kt * 32, &Ash[c1 * 512]);
    gload_lds16(Al  + aOff0 + kt * 32, &Asl[c0 * 512]);
    gload_lds16(Al  + aOff1 + kt * 32, &Asl[c1 * 512]);
    gload_lds16(BhT + bOff0 + kt * 32, &Bsh[c0 * 512]);
    gload_lds16(BhT + bOff1 + kt * 32, &Bsh[c1 * 512]);
    gload_lds16(BlT + bOff0 + kt * 32, &Bsl[c0 * 512]);
    gload_lds16(BlT + bOff1 + kt * 32, &Bsl[c1 * 512]);
    __syncthreads();
    short8 aH[4], aL[4], bH[4], bL[4];
    for (int m = 0; m < 4; ++m){
      int o = (wr * 64 + m * 16 + (l & 15)) * 32 + (l >> 4) * 8;
      aH[m] = *(const short8*)&Ash[o];
      aL[m] = *(const short8*)&Asl[o];
    }
    for (int n = 0; n < 4; ++n){
      int o = (wc * 64 + n * 16 + (l & 15)) * 32 + (l >> 4) * 8;
      bH[n] = *(const short8*)&Bsh[o];
      bL[n] = *(const short8*)&Bsl[o];
    }
    for (int m = 0; m < 4; ++m)
      for (int n = 0; n < 4; ++n){
        acc[m][n] = __builtin_amdgcn_mfma_f32_16x16x32_bf16(aH[m], bH[n], acc[m][n], 0, 0, 0);
        acc[m][n] = __builtin_amdgcn_mfma_f32_16x16x32_bf16(aH[m], bL[n], acc[m][n], 0, 0, 0);
        acc[m][n] = __builtin_amdgcn_mfma_f32_16x16x32_bf16(aL[m], bH[n], acc[m][n], 0, 0, 0);
      }
  }

  for (int nf = 0; nf < 4; ++nf){
    int ncol = ntile + wc * 64 + nf * 16 + (l & 15);
    float bv = bias[ncol];
    for (int m = 0; m < 4; ++m){
      int rbase = mtile + wr * 64 + m * 16 + (l >> 4) * 4;
      for (int r = 0; r < 4; ++r)
        out[(size_t)(rbase + r) * 1024 + ncol] = acc[m][nf][r] + bv;
    }
  }
}

// =====================================================================
extern "C" void kernel_launch(void* const* d_in, const int* in_sizes, int n_in,
                              void* d_out, int out_size, void* d_ws, size_t ws_size,
                              hipStream_t stream){
  const float* x     = (const float*)d_in[0];
  const float* w_qkv = (const float*)d_in[1];
  const float* b_qkv = (const float*)d_in[2];
  const float* w_out = (const float*)d_in[3];
  const float* b_out = (const float*)d_in[4];
  float* out = (float*)d_out;
  char* ws = (char*)d_ws;

  size_t off = 0;
  auto alloc = [&](size_t bytes){ size_t o = off; off += (bytes + 255) & ~(size_t)255; return o; };
  const size_t SZ_X   = (size_t)8192 * 1024 * 2;   // 16 MiB
  const size_t SZ_QKV = (size_t)64 * 2048 * 64 * 2;
  size_t o_xb  = alloc(SZ_X);                      // xb; reused as Ohi after G1
  size_t o_wq  = alloc((size_t)3072 * 1024 * 2);
  size_t o_q   = alloc(SZ_QKV);
  size_t o_k   = alloc(SZ_QKV);
  size_t o_v   = alloc(SZ_QKV);
  size_t o_olo = alloc(SZ_X);
  size_t o_wh  = alloc((size_t)1024 * 1024 * 2);
  size_t o_wl  = alloc((size_t)1024 * 1024 * 2);

  ushort* xb  = (ushort*)(ws + o_xb);
  ushort* wqT = (ushort*)(ws + o_wq);
  ushort* Qb  = (ushort*)(ws + o_q);
  ushort* Kb  = (ushort*)(ws + o_k);
  ushort* Vb  = (ushort*)(ws + o_v);
  ushort* Ohi = (ushort*)(ws + o_xb);              // alias: xb dead after G1
  ushort* Olo = (ushort*)(ws + o_olo);
  ushort* WhT = (ushort*)(ws + o_wh);
  ushort* WlT = (ushort*)(ws + o_wl);

  cast_bf16<<<8192, 256, 0, stream>>>((const float4*)x, xb, 8192 * 1024 / 4);
  transpose_cast<0><<<dim3(48, 16), 256, 0, stream>>>(w_qkv, wqT, nullptr, 1024, 3072);
  transpose_cast<1><<<dim3(16, 16), 256, 0, stream>>>(w_out, WhT, WlT, 1024, 1024);
  gemm_qkv<<<dim3(24, 64), 256, 0, stream>>>(xb, wqT, b_qkv, Qb, Kb, Vb);
  attn_fwd<<<dim3(32, 64), 256, 0, stream>>>(Qb, Kb, Vb, Ohi, Olo);
  gemm_out<<<dim3(8, 64), 256, 0, stream>>>(Ohi, Olo, WhT, WlT, b_out, out);
}

// Round 4
// 455.921 us; speedup vs baseline: 1.0586x; 1.0343x over previous
//
#include <hip/hip_runtime.h>
#include <hip/hip_bf16.h>

typedef __attribute__((ext_vector_type(8))) short short8;
typedef __attribute__((ext_vector_type(4))) float f32x4;
typedef __attribute__((ext_vector_type(4))) unsigned short ushort4v;
typedef unsigned short ushort;

#define DEVI static __device__ __forceinline__

// ---------- bf16 helpers (RNE) ----------
DEVI ushort f2bf(float f){
  union { float f; unsigned u; } v; v.f = f;
  unsigned r = v.u + 0x7fffu + ((v.u >> 16) & 1u);
  return (ushort)(r >> 16);
}
DEVI float bf2f(ushort u){
  union { unsigned u; float f; } v; v.u = ((unsigned)u) << 16;
  return v.f;
}

// ---------- async global->LDS (16B per lane, linear dest) ----------
DEVI void gload_lds16(const void* g, void* l){
  __builtin_amdgcn_global_load_lds(
      (const __attribute__((address_space(1))) void*)g,
      (__attribute__((address_space(3))) void*)l, 16, 0, 0);
}

// =====================================================================
// P1: cast fp32 -> bf16 (vectorized)
// =====================================================================
__global__ __launch_bounds__(256) void cast_bf16(const float4* __restrict__ in,
                                                 ushort* __restrict__ out, int n4){
  int i = blockIdx.x * 256 + threadIdx.x;
  if (i < n4){
    float4 v = in[i];
    ushort4v o = { f2bf(v.x), f2bf(v.y), f2bf(v.z), f2bf(v.w) };
    *(ushort4v*)&out[(size_t)i * 4] = o;
  }
}

// =====================================================================
// P2: transpose + cast fp32[R][C] -> bf16[C][R] (optional hi/lo split)
// =====================================================================
template<int SPLIT>
__global__ __launch_bounds__(256) void transpose_cast(const float* __restrict__ in,
                                                      ushort* __restrict__ outT,
                                                      ushort* __restrict__ outLo,
                                                      int R, int C){
  __shared__ float tile[64][65];
  const int r0 = blockIdx.y * 64, c0 = blockIdx.x * 64;
  const int t = threadIdx.x;
  for (int it = 0; it < 16; ++it){
    int idx = it * 256 + t; int rr = idx >> 6, cc = idx & 63;
    tile[rr][cc] = in[(size_t)(r0 + rr) * C + (c0 + cc)];
  }
  __syncthreads();
  for (int it = 0; it < 16; ++it){
    int idx = it * 256 + t; int oc = idx >> 6, orow = idx & 63;
    float v = tile[orow][oc];
    ushort hi = f2bf(v);
    size_t o = (size_t)(c0 + oc) * R + (r0 + orow);
    outT[o] = hi;
    if (SPLIT) outLo[o] = f2bf(v - bf2f(hi));
  }
}

// =====================================================================
// G1a: Q/K projection (cols 0..2047).  Q is pre-scaled by 0.125*log2(e)
// so the attention softmax runs in the exp2 domain with no per-score mul.
// =====================================================================
__global__ __launch_bounds__(256) void gemm_qk(const ushort* __restrict__ A,
                                               const ushort* __restrict__ BT,
                                               const float* __restrict__ bias,
                                               ushort* __restrict__ Qo,
                                               ushort* __restrict__ Ko){
  constexpr int K = 1024;
  constexpr float QSCALE = 0.18033688011112042f;   // 0.125 * log2(e)
  __shared__ __align__(16) ushort As[128 * 32];
  __shared__ __align__(16) ushort Bs[128 * 32];
  const int tid = threadIdx.x, w = tid >> 6, l = tid & 63;
  const int wr = w >> 1, wc = w & 1;
  const int mtile = blockIdx.y * 128, ntile = blockIdx.x * 128;

  f32x4 acc[4][4];
  for (int m = 0; m < 4; ++m) for (int n = 0; n < 4; ++n)
    for (int r = 0; r < 4; ++r) acc[m][n][r] = 0.f;

  const int c0 = 2 * w, c1 = 2 * w + 1;
  const ushort* aG0 = A  + (size_t)(mtile + c0 * 16 + (l >> 2)) * K + (l & 3) * 8;
  const ushort* aG1 = A  + (size_t)(mtile + c1 * 16 + (l >> 2)) * K + (l & 3) * 8;
  const ushort* bG0 = BT + (size_t)(ntile + c0 * 16 + (l >> 2)) * K + (l & 3) * 8;
  const ushort* bG1 = BT + (size_t)(ntile + c1 * 16 + (l >> 2)) * K + (l & 3) * 8;

  for (int kt = 0; kt < K / 32; ++kt){
    __syncthreads();
    gload_lds16(aG0 + kt * 32, &As[c0 * 512]);
    gload_lds16(aG1 + kt * 32, &As[c1 * 512]);
    gload_lds16(bG0 + kt * 32, &Bs[c0 * 512]);
    gload_lds16(bG1 + kt * 32, &Bs[c1 * 512]);
    __syncthreads();
    short8 aF[4], bF[4];
    for (int m = 0; m < 4; ++m)
      aF[m] = *(const short8*)&As[(wr * 64 + m * 16 + (l & 15)) * 32 + (l >> 4) * 8];
    for (int n = 0; n < 4; ++n)
      bF[n] = *(const short8*)&Bs[(wc * 64 + n * 16 + (l & 15)) * 32 + (l >> 4) * 8];
    for (int m = 0; m < 4; ++m)
      for (int n = 0; n < 4; ++n)
        acc[m][n] = __builtin_amdgcn_mfma_f32_16x16x32_bf16(aF[m], bF[n], acc[m][n], 0, 0, 0);
  }

  for (int nf = 0; nf < 4; ++nf){
    int ncol = ntile + wc * 64 + nf * 16 + (l & 15);
    float bv = bias[ncol];
    int isQ = (ncol < 1024) ? 1 : 0;
    int h = (ncol >> 6) & 15, d = ncol & 63;
    ushort* dst = isQ ? Qo : Ko;
    float sc = isQ ? QSCALE : 1.0f;
    for (int m = 0; m < 4; ++m){
      int rbase = mtile + wr * 64 + m * 16 + (l >> 4) * 4;
      for (int r = 0; r < 4; ++r){
        int row = rbase + r;
        int b = row >> 11, t = row & 2047;
        dst[((size_t)(b * 16 + h) * 2048 + t) * 64 + d] = f2bf((acc[m][nf][r] + bv) * sc);
      }
    }
  }
}

// =====================================================================
// G1b: V projection (cols 2048..3071) writing V TRANSPOSED:
// VT[bh][d][t] — so attention can stage V via global_load_lds like K.
// Per-block 128x128 LDS transpose in the epilogue.
// =====================================================================
__global__ __launch_bounds__(256) void gemm_vT(const ushort* __restrict__ A,
                                               const ushort* __restrict__ BT,
                                               const float* __restrict__ bias,
                                               ushort* __restrict__ VT){
  constexpr int K = 1024;
  __shared__ __align__(16) ushort As[128 * 32];
  __shared__ __align__(16) ushort Bs[128 * 32];
  __shared__ __align__(16) ushort LT[128][136];    // [col][t], 16B-aligned rows
  const int tid = threadIdx.x, w = tid >> 6, l = tid & 63;
  const int wr = w >> 1, wc = w & 1;
  const int mtile = blockIdx.y * 128, ntv = blockIdx.x * 128;  // ntv in 0..1023

  f32x4 acc[4][4];
  for (int m = 0; m < 4; ++m) for (int n = 0; n < 4; ++n)
    for (int r = 0; r < 4; ++r) acc[m][n][r] = 0.f;

  const int c0 = 2 * w, c1 = 2 * w + 1;
  const ushort* aG0 = A  + (size_t)(mtile + c0 * 16 + (l >> 2)) * K + (l & 3) * 8;
  const ushort* aG1 = A  + (size_t)(mtile + c1 * 16 + (l >> 2)) * K + (l & 3) * 8;
  const ushort* bG0 = BT + (size_t)(2048 + ntv + c0 * 16 + (l >> 2)) * K + (l & 3) * 8;
  const ushort* bG1 = BT + (size_t)(2048 + ntv + c1 * 16 + (l >> 2)) * K + (l & 3) * 8;

  for (int kt = 0; kt < K / 32; ++kt){
    __syncthreads();
    gload_lds16(aG0 + kt * 32, &As[c0 * 512]);
    gload_lds16(aG1 + kt * 32, &As[c1 * 512]);
    gload_lds16(bG0 + kt * 32, &Bs[c0 * 512]);
    gload_lds16(bG1 + kt * 32, &Bs[c1 * 512]);
    __syncthreads();
    short8 aF[4], bF[4];
    for (int m = 0; m < 4; ++m)
      aF[m] = *(const short8*)&As[(wr * 64 + m * 16 + (l & 15)) * 32 + (l >> 4) * 8];
    for (int n = 0; n < 4; ++n)
      bF[n] = *(const short8*)&Bs[(wc * 64 + n * 16 + (l & 15)) * 32 + (l >> 4) * 8];
    for (int m = 0; m < 4; ++m)
      for (int n = 0; n < 4; ++n)
        acc[m][n] = __builtin_amdgcn_mfma_f32_16x16x32_bf16(aF[m], bF[n], acc[m][n], 0, 0, 0);
  }

  // epilogue: acc -> LT[col][t_local], then coalesced VT[bh][d][t] writes
  for (int nf = 0; nf < 4; ++nf){
    int cl = wc * 64 + nf * 16 + (l & 15);
    float bv = bias[2048 + ntv + cl];
    for (int m = 0; m < 4; ++m){
      int rl = wr * 64 + m * 16 + (l >> 4) * 4;
      for (int r = 0; r < 4; ++r)
        LT[cl][rl + r] = f2bf(acc[m][nf][r] + bv);
    }
  }
  __syncthreads();
  const int b = mtile >> 11, t0 = mtile & 2047;
  for (int p = 0; p < 8; ++p){
    int idx = p * 256 + tid;
    int col = idx >> 4, tc = idx & 15;
    int ncol = ntv + col;
    int h = ncol >> 6, d = ncol & 63;
    short8 v = *(const short8*)&LT[col][tc * 8];
    *(short8*)&VT[((size_t)(b * 16 + h) * 64 + d) * 2048 + t0 + tc * 8] = v;
  }
}

// =====================================================================
// A: flash attention. K and V^T both staged via global_load_lds with the
// XOR swizzle (linear dest, inverse-swizzled source, swizzled b128 read).
// Q pre-scaled -> softmax in exp2 domain. P->bf16 via v_cvt_pk_bf16_f32.
// =====================================================================
__global__ __launch_bounds__(256) void attn_fwd(const ushort* __restrict__ Q,
                                                const ushort* __restrict__ Kb,
                                                const ushort* __restrict__ VT,
                                                ushort* __restrict__ Ohi,
                                                ushort* __restrict__ Olo){
  __shared__ __align__(16) ushort Ks[64 * 64];     // [key][d] swizzled
  __shared__ __align__(16) ushort Vs[64 * 64];     // [d][key] swizzled
  __shared__ __align__(16) ushort Ps[4][16][72];   // per-wave P, padded
  const int tid = threadIdx.x, w = tid >> 6, l = tid & 63;
  const int bh = blockIdx.y, qbase = blockIdx.x * 64;
  const ushort* Qp = Q  + (size_t)bh * 2048 * 64;
  const ushort* Kp = Kb + (size_t)bh * 2048 * 64;
  const ushort* Vp = VT + (size_t)bh * 64 * 2048;  // [d][t]

  constexpr float DEFER_THR = 8.0f;                // 2^8 P-value headroom

  const int qrow = qbase + w * 16 + (l & 15);
  short8 qf0 = *(const short8*)&Qp[(size_t)qrow * 64 + (l >> 4) * 8];
  short8 qf1 = *(const short8*)&Qp[(size_t)qrow * 64 + 32 + (l >> 4) * 8];

  float mrow[4], lrow[4];
  f32x4 oacc[4];
  for (int r = 0; r < 4; ++r){ mrow[r] = -1e30f; lrow[r] = 0.f; }
  for (int c = 0; c < 4; ++c) for (int r = 0; r < 4; ++r) oacc[c][r] = 0.f;

  const int c0 = 2 * w, c1 = 2 * w + 1;
  // staging: inverse-swizzled source column (16B units): (l&7) ^ (l>>3)
  const int ssrc = ((l & 7) ^ (l >> 3)) * 8;
  const int sr0 = c0 * 8 + (l >> 3), sr1 = c1 * 8 + (l >> 3);
  // swizzled read col XOR (ushort units)
  const int rrow = l & 15;
  const int rxor = (rrow & 7) * 8;

  for (int kt = 0; kt < 32; ++kt){
    const int kb = kt * 64;
    __syncthreads();                               // prev-iter LDS reads done
    gload_lds16(Kp + (size_t)(kb + sr0) * 64 + ssrc, &Ks[c0 * 512]);
    gload_lds16(Kp + (size_t)(kb + sr1) * 64 + ssrc, &Ks[c1 * 512]);
    gload_lds16(Vp + (size_t)sr0 * 2048 + kb + ssrc, &Vs[c0 * 512]);
    gload_lds16(Vp + (size_t)sr1 * 2048 + kb + ssrc, &Vs[c1 * 512]);
    __syncthreads();                               // K + V staged

    f32x4 s[4];
    for (int nf = 0; nf < 4; ++nf) for (int r = 0; r < 4; ++r) s[nf][r] = 0.f;
    __builtin_amdgcn_s_setprio(1);
    for (int nf = 0; nf < 4; ++nf){
      int rb = (nf * 16 + rrow) * 64;
      short8 kf0 = *(const short8*)&Ks[rb + (((l >> 4) * 8)      ^ rxor)];
      short8 kf1 = *(const short8*)&Ks[rb + (((l >> 4) * 8 + 32) ^ rxor)];
      s[nf] = __builtin_amdgcn_mfma_f32_16x16x32_bf16(qf0, kf0, s[nf], 0, 0, 0);
      s[nf] = __builtin_amdgcn_mfma_f32_16x16x32_bf16(qf1, kf1, s[nf], 0, 0, 0);
    }
    __builtin_amdgcn_s_setprio(0);

    float pmax[4];
    for (int r = 0; r < 4; ++r) pmax[r] = fmaxf(fmaxf(s[0][r], s[1][r]), fmaxf(s[2][r], s[3][r]));
    for (int off = 1; off < 16; off <<= 1)
      for (int r = 0; r < 4; ++r) pmax[r] = fmaxf(pmax[r], __shfl_xor(pmax[r], off));

    // defer-max: skip rescale when per-tile max growth is small (T13)
    bool defer = true;
    for (int r = 0; r < 4; ++r) defer = defer && (pmax[r] <= mrow[r] + DEFER_THR);
    if (!__all(defer)){
      for (int r = 0; r < 4; ++r){
        float mn = fmaxf(mrow[r], pmax[r]);
        float alpha = exp2f(mrow[r] - mn);
        mrow[r] = mn;
        lrow[r] *= alpha;
        for (int c = 0; c < 4; ++c) oacc[c][r] *= alpha;
      }
    }

    float rsum[4];
    for (int r = 0; r < 4; ++r) rsum[r] = 0.f;
    for (int nf = 0; nf < 4; ++nf)
      for (int r = 0; r < 4; ++r){
        float p = exp2f(s[nf][r] - mrow[r]);
        s[nf][r] = p; rsum[r] += p;
      }
    // P -> bf16 via packed hw convert (2 floats / instr), wave-private Ps
    for (int nf = 0; nf < 4; ++nf){
      unsigned pk01, pk23;
      asm("v_cvt_pk_bf16_f32 %0, %1, %2" : "=v"(pk01) : "v"(s[nf][0]), "v"(s[nf][1]));
      asm("v_cvt_pk_bf16_f32 %0, %1, %2" : "=v"(pk23) : "v"(s[nf][2]), "v"(s[nf][3]));
      int key = nf * 16 + (l & 15), q0 = (l >> 4) * 4;
      Ps[w][q0 + 0][key] = (ushort)pk01;
      Ps[w][q0 + 1][key] = (ushort)(pk01 >> 16);
      Ps[w][q0 + 2][key] = (ushort)pk23;
      Ps[w][q0 + 3][key] = (ushort)(pk23 >> 16);
    }
    for (int off = 1; off < 16; off <<= 1)
      for (int r = 0; r < 4; ++r) rsum[r] += __shfl_xor(rsum[r], off);
    for (int r = 0; r < 4; ++r) lrow[r] += rsum[r];
    // no barrier: Ps is wave-private (lgkmcnt orders ds_write->ds_read)

    __builtin_amdgcn_s_setprio(1);
    for (int st = 0; st < 2; ++st){
      short8 pf = *(const short8*)&Ps[w][(l & 15)][st * 32 + (l >> 4) * 8];
      for (int c = 0; c < 4; ++c){
        int vb = (c * 16 + rrow) * 64;
        short8 vf = *(const short8*)&Vs[vb + ((st * 32 + (l >> 4) * 8) ^ rxor)];
        oacc[c] = __builtin_amdgcn_mfma_f32_16x16x32_bf16(pf, vf, oacc[c], 0, 0, 0);
      }
    }
    __builtin_amdgcn_s_setprio(0);
  }

  const int b = bh >> 4, h = bh & 15;
  for (int r = 0; r < 4; ++r){
    float inv = 1.0f / lrow[r];
    int q = qbase + w * 16 + (l >> 4) * 4 + r;
    size_t rowoff = ((size_t)(b * 2048 + q)) * 1024 + h * 64;
    for (int c = 0; c < 4; ++c){
      float val = oacc[c][r] * inv;
      ushort hi = f2bf(val);
      Ohi[rowoff + c * 16 + (l & 15)] = hi;
      Olo[rowoff + c * 16 + (l & 15)] = f2bf(val - bf2f(hi));
    }
  }
}

// =====================================================================
// G2: output projection with bf16 hi/lo split (3 MFMAs per product)
// =====================================================================
__global__ __launch_bounds__(256) void gemm_out(const ushort* __restrict__ Ah,
                                                const ushort* __restrict__ Al,
                                                const ushort* __restrict__ BhT,
                                                const ushort* __restrict__ BlT,
                                                const float* __restrict__ bias,
                                                float* __restrict__ out){
  constexpr int K = 1024;
  __shared__ __align__(16) ushort Ash[128 * 32], Asl[128 * 32];
  __shared__ __align__(16) ushort Bsh[128 * 32], Bsl[128 * 32];
  const int tid = threadIdx.x, w = tid >> 6, l = tid & 63;
  const int wr = w >> 1, wc = w & 1;
  const int mtile = blockIdx.y * 128, ntile = blockIdx.x * 128;

  f32x4 acc[4][4];
  for (int m = 0; m < 4; ++m) for (int n = 0; n < 4; ++n)
    for (int r = 0; r < 4; ++r) acc[m][n][r] = 0.f;

  const int c0 = 2 * w, c1 = 2 * w + 1;
  const size_t aOff0 = (size_t)(mtile + c0 * 16 + (l >> 2)) * K + (l & 3) * 8;
  const size_t aOff1 = (size_t)(mtile + c1 * 16 + (l >> 2)) * K + (l & 3) * 8;
  const size_t bOff0 = (size_t)(ntile + c0 * 16 + (l >> 2)) * K + (l & 3) * 8;
  const size_t bOff1 = (size_t)(ntile + c1 * 16 + (l >> 2)) * K + (l & 3) * 8;

  for (int kt = 0; kt < K / 32; ++kt){
    __syncthreads();
    gload_lds16(Ah  + aOff0 + kt * 32, &Ash[c0 * 512]);
    gload_lds16(Ah  + aOff1 + kt * 32, &Ash[c1 * 512]);
    gload_lds16(Al  + aOff0 + kt * 32, &Asl[c0 * 512]);
    gload_lds16(Al  + aOff1 + kt * 32, &Asl[c1 * 512]);
    gload_lds16(BhT + bOff0 + kt * 32, &Bsh[c0 * 512]);
    gload_lds16(BhT + bOff1 + kt * 32, &Bsh[c1 * 512]);
    gload_lds16(BlT + bOff0 + kt * 32, &Bsl[c0 * 512]);
    gload_lds16(BlT + bOff1 + kt * 32, &Bsl[c1 * 512]);
    __syncthreads();
    short8 aH[4], aL[4], bH[4], bL[4];
    for (int m = 0; m < 4; ++m){
      int o = (wr * 64 + m * 16 + (l & 15)) * 32 + (l >> 4) * 8;
      aH[m] = *(const short8*)&Ash[o];
      aL[m] = *(const short8*)&Asl[o];
    }
    for (int n = 0; n < 4; ++n){
      int o = (wc * 64 + n * 16 + (l & 15)) * 32 + (l >> 4) * 8;
      bH[n] = *(const short8*)&Bsh[o];
      bL[n] = *(const short8*)&Bsl[o];
    }
    for (int m = 0; m < 4; ++m)
      for (int n = 0; n < 4; ++n){
        acc[m][n] = __builtin_amdgcn_mfma_f32_16x16x32_bf16(aH[m], bH[n], acc[m][n], 0, 0, 0);
        acc[m][n] = __builtin_amdgcn_mfma_f32_16x16x32_bf16(aH[m], bL[n], acc[m][n], 0, 0, 0);
        acc[m][n] = __builtin_amdgcn_mfma_f32_16x16x32_bf16(aL[m], bH[n], acc[m][n], 0, 0, 0);
      }
  }

  for (int nf = 0; nf < 4; ++nf){
    int ncol = ntile + wc * 64 + nf * 16 + (l & 15);
    float bv = bias[ncol];
    for (int m = 0; m < 4; ++m){
      int rbase = mtile + wr * 64 + m * 16 + (l >> 4) * 4;
      for (int r = 0; r < 4; ++r)
        out[(size_t)(rbase + r) * 1024 + ncol] = acc[m][nf][r] + bv;
    }
  }
}

// =====================================================================
extern "C" void kernel_launch(void* const* d_in, const int* in_sizes, int n_in,
                              void* d_out, int out_size, void* d_ws, size_t ws_size,
                              hipStream_t stream){
  const float* x     = (const float*)d_in[0];
  const float* w_qkv = (const float*)d_in[1];
  const float* b_qkv = (const float*)d_in[2];
  const float* w_out = (const float*)d_in[3];
  const float* b_out = (const float*)d_in[4];
  float* out = (float*)d_out;
  char* ws = (char*)d_ws;

  size_t off = 0;
  auto alloc = [&](size_t bytes){ size_t o = off; off += (bytes + 255) & ~(size_t)255; return o; };
  const size_t SZ_X   = (size_t)8192 * 1024 * 2;   // 16 MiB
  const size_t SZ_QKV = (size_t)64 * 2048 * 64 * 2;
  size_t o_xb  = alloc(SZ_X);                      // xb; reused as Ohi after G1
  size_t o_wq  = alloc((size_t)3072 * 1024 * 2);
  size_t o_q   = alloc(SZ_QKV);
  size_t o_k   = alloc(SZ_QKV);
  size_t o_v   = alloc(SZ_QKV);                    // VT[bh][d][t]
  size_t o_olo = alloc(SZ_X);
  size_t o_wh  = alloc((size_t)1024 * 1024 * 2);
  size_t o_wl  = alloc((size_t)1024 * 1024 * 2);

  ushort* xb  = (ushort*)(ws + o_xb);
  ushort* wqT = (ushort*)(ws + o_wq);
  ushort* Qb  = (ushort*)(ws + o_q);
  ushort* Kb  = (ushort*)(ws + o_k);
  ushort* VTb = (ushort*)(ws + o_v);
  ushort* Ohi = (ushort*)(ws + o_xb);              // alias: xb dead after G1
  ushort* Olo = (ushort*)(ws + o_olo);
  ushort* WhT = (ushort*)(ws + o_wh);
  ushort* WlT = (ushort*)(ws + o_wl);

  cast_bf16<<<8192, 256, 0, stream>>>((const float4*)x, xb, 8192 * 1024 / 4);
  transpose_cast<0><<<dim3(48, 16), 256, 0, stream>>>(w_qkv, wqT, nullptr, 1024, 3072);
  transpose_cast<1><<<dim3(16, 16), 256, 0, stream>>>(w_out, WhT, WlT, 1024, 1024);
  gemm_qk<<<dim3(16, 64), 256, 0, stream>>>(xb, wqT, b_qkv, Qb, Kb);
  gemm_vT<<<dim3(8, 64), 256, 0, stream>>>(xb, wqT, b_qkv, VTb);
  attn_fwd<<<dim3(32, 64), 256, 0, stream>>>(Qb, Kb, VTb, Ohi, Olo);
  gemm_out<<<dim3(8, 64), 256, 0, stream>>>(Ohi, Olo, WhT, WlT, b_out, out);
}

// Round 6
// 368.671 us; speedup vs baseline: 1.3091x; 1.2367x over previous
//
#include <hip/hip_runtime.h>
#include <hip/hip_bf16.h>

typedef __attribute__((ext_vector_type(8))) short short8;
typedef __attribute__((ext_vector_type(4))) float f32x4;
typedef __attribute__((ext_vector_type(4))) unsigned short ushort4v;
typedef unsigned short ushort;

#define DEVI static __device__ __forceinline__

// ---------- bf16 helpers (RNE) ----------
DEVI ushort f2bf(float f){
  union { float f; unsigned u; } v; v.f = f;
  unsigned r = v.u + 0x7fffu + ((v.u >> 16) & 1u);
  return (ushort)(r >> 16);
}
DEVI float bf2f(ushort u){
  union { unsigned u; float f; } v; v.u = ((unsigned)u) << 16;
  return v.f;
}

// ---------- async global->LDS (16B per lane, linear dest) ----------
DEVI void gload_lds16(const void* g, void* l){
  __builtin_amdgcn_global_load_lds(
      (const __attribute__((address_space(1))) void*)g,
      (__attribute__((address_space(3))) void*)l, 16, 0, 0);
}

// =====================================================================
// P1: cast fp32 -> bf16 (vectorized)
// =====================================================================
__global__ __launch_bounds__(256) void cast_bf16(const float4* __restrict__ in,
                                                 ushort* __restrict__ out, int n4){
  int i = blockIdx.x * 256 + threadIdx.x;
  if (i < n4){
    float4 v = in[i];
    ushort4v o = { f2bf(v.x), f2bf(v.y), f2bf(v.z), f2bf(v.w) };
    *(ushort4v*)&out[(size_t)i * 4] = o;
  }
}

// =====================================================================
// P2: transpose + cast fp32[R][C] -> bf16[C][R] (optional hi/lo split)
// =====================================================================
template<int SPLIT>
__global__ __launch_bounds__(256) void transpose_cast(const float* __restrict__ in,
                                                      ushort* __restrict__ outT,
                                                      ushort* __restrict__ outLo,
                                                      int R, int C){
  __shared__ float tile[64][65];
  const int r0 = blockIdx.y * 64, c0 = blockIdx.x * 64;
  const int t = threadIdx.x;
  for (int it = 0; it < 16; ++it){
    int idx = it * 256 + t; int rr = idx >> 6, cc = idx & 63;
    tile[rr][cc] = in[(size_t)(r0 + rr) * C + (c0 + cc)];
  }
  __syncthreads();
  for (int it = 0; it < 16; ++it){
    int idx = it * 256 + t; int oc = idx >> 6, orow = idx & 63;
    float v = tile[orow][oc];
    ushort hi = f2bf(v);
    size_t o = (size_t)(c0 + oc) * R + (r0 + orow);
    outT[o] = hi;
    if (SPLIT) outLo[o] = f2bf(v - bf2f(hi));
  }
}

// =====================================================================
// G1a: Q/K projection (cols 0..2047).  Q is pre-scaled by 0.125*log2(e)
// so the attention softmax runs in the exp2 domain with no per-score mul.
// =====================================================================
__global__ __launch_bounds__(256) void gemm_qk(const ushort* __restrict__ A,
                                               const ushort* __restrict__ BT,
                                               const float* __restrict__ bias,
                                               ushort* __restrict__ Qo,
                                               ushort* __restrict__ Ko){
  constexpr int K = 1024;
  constexpr float QSCALE = 0.18033688011112042f;   // 0.125 * log2(e)
  __shared__ __align__(16) ushort As[128 * 32];
  __shared__ __align__(16) ushort Bs[128 * 32];
  const int tid = threadIdx.x, w = tid >> 6, l = tid & 63;
  const int wr = w >> 1, wc = w & 1;
  const int mtile = blockIdx.y * 128, ntile = blockIdx.x * 128;

  f32x4 acc[4][4];
  for (int m = 0; m < 4; ++m) for (int n = 0; n < 4; ++n)
    for (int r = 0; r < 4; ++r) acc[m][n][r] = 0.f;

  const int c0 = 2 * w, c1 = 2 * w + 1;
  const ushort* aG0 = A  + (size_t)(mtile + c0 * 16 + (l >> 2)) * K + (l & 3) * 8;
  const ushort* aG1 = A  + (size_t)(mtile + c1 * 16 + (l >> 2)) * K + (l & 3) * 8;
  const ushort* bG0 = BT + (size_t)(ntile + c0 * 16 + (l >> 2)) * K + (l & 3) * 8;
  const ushort* bG1 = BT + (size_t)(ntile + c1 * 16 + (l >> 2)) * K + (l & 3) * 8;

  for (int kt = 0; kt < K / 32; ++kt){
    __syncthreads();
    gload_lds16(aG0 + kt * 32, &As[c0 * 512]);
    gload_lds16(aG1 + kt * 32, &As[c1 * 512]);
    gload_lds16(bG0 + kt * 32, &Bs[c0 * 512]);
    gload_lds16(bG1 + kt * 32, &Bs[c1 * 512]);
    __syncthreads();
    short8 aF[4], bF[4];
    for (int m = 0; m < 4; ++m)
      aF[m] = *(const short8*)&As[(wr * 64 + m * 16 + (l & 15)) * 32 + (l >> 4) * 8];
    for (int n = 0; n < 4; ++n)
      bF[n] = *(const short8*)&Bs[(wc * 64 + n * 16 + (l & 15)) * 32 + (l >> 4) * 8];
    for (int m = 0; m < 4; ++m)
      for (int n = 0; n < 4; ++n)
        acc[m][n] = __builtin_amdgcn_mfma_f32_16x16x32_bf16(aF[m], bF[n], acc[m][n], 0, 0, 0);
  }

  for (int nf = 0; nf < 4; ++nf){
    int ncol = ntile + wc * 64 + nf * 16 + (l & 15);
    float bv = bias[ncol];
    int isQ = (ncol < 1024) ? 1 : 0;
    int h = (ncol >> 6) & 15, d = ncol & 63;
    ushort* dst = isQ ? Qo : Ko;
    float sc = isQ ? QSCALE : 1.0f;
    for (int m = 0; m < 4; ++m){
      int rbase = mtile + wr * 64 + m * 16 + (l >> 4) * 4;
      for (int r = 0; r < 4; ++r){
        int row = rbase + r;
        int b = row >> 11, t = row & 2047;
        dst[((size_t)(b * 16 + h) * 2048 + t) * 64 + d] = f2bf((acc[m][nf][r] + bv) * sc);
      }
    }
  }
}

// =====================================================================
// G1b: V projection (cols 2048..3071) writing V TRANSPOSED:
// VT[bh][d][t] — so attention can stage V via global_load_lds like K.
// =====================================================================
__global__ __launch_bounds__(256) void gemm_vT(const ushort* __restrict__ A,
                                               const ushort* __restrict__ BT,
                                               const float* __restrict__ bias,
                                               ushort* __restrict__ VT){
  constexpr int K = 1024;
  __shared__ __align__(16) ushort As[128 * 32];
  __shared__ __align__(16) ushort Bs[128 * 32];
  __shared__ __align__(16) ushort LT[128][136];    // [col][t], 16B-aligned rows
  const int tid = threadIdx.x, w = tid >> 6, l = tid & 63;
  const int wr = w >> 1, wc = w & 1;
  const int mtile = blockIdx.y * 128, ntv = blockIdx.x * 128;  // ntv in 0..1023

  f32x4 acc[4][4];
  for (int m = 0; m < 4; ++m) for (int n = 0; n < 4; ++n)
    for (int r = 0; r < 4; ++r) acc[m][n][r] = 0.f;

  const int c0 = 2 * w, c1 = 2 * w + 1;
  const ushort* aG0 = A  + (size_t)(mtile + c0 * 16 + (l >> 2)) * K + (l & 3) * 8;
  const ushort* aG1 = A  + (size_t)(mtile + c1 * 16 + (l >> 2)) * K + (l & 3) * 8;
  const ushort* bG0 = BT + (size_t)(2048 + ntv + c0 * 16 + (l >> 2)) * K + (l & 3) * 8;
  const ushort* bG1 = BT + (size_t)(2048 + ntv + c1 * 16 + (l >> 2)) * K + (l & 3) * 8;

  for (int kt = 0; kt < K / 32; ++kt){
    __syncthreads();
    gload_lds16(aG0 + kt * 32, &As[c0 * 512]);
    gload_lds16(aG1 + kt * 32, &As[c1 * 512]);
    gload_lds16(bG0 + kt * 32, &Bs[c0 * 512]);
    gload_lds16(bG1 + kt * 32, &Bs[c1 * 512]);
    __syncthreads();
    short8 aF[4], bF[4];
    for (int m = 0; m < 4; ++m)
      aF[m] = *(const short8*)&As[(wr * 64 + m * 16 + (l & 15)) * 32 + (l >> 4) * 8];
    for (int n = 0; n < 4; ++n)
      bF[n] = *(const short8*)&Bs[(wc * 64 + n * 16 + (l & 15)) * 32 + (l >> 4) * 8];
    for (int m = 0; m < 4; ++m)
      for (int n = 0; n < 4; ++n)
        acc[m][n] = __builtin_amdgcn_mfma_f32_16x16x32_bf16(aF[m], bF[n], acc[m][n], 0, 0, 0);
  }

  // epilogue: acc -> LT[col][t_local], then coalesced VT[bh][d][t] writes
  for (int nf = 0; nf < 4; ++nf){
    int cl = wc * 64 + nf * 16 + (l & 15);
    float bv = bias[2048 + ntv + cl];
    for (int m = 0; m < 4; ++m){
      int rl = wr * 64 + m * 16 + (l >> 4) * 4;
      for (int r = 0; r < 4; ++r)
        LT[cl][rl + r] = f2bf(acc[m][nf][r] + bv);
    }
  }
  __syncthreads();
  const int b = mtile >> 11, t0 = mtile & 2047;
  for (int p = 0; p < 8; ++p){
    int idx = p * 256 + tid;
    int col = idx >> 4, tc = idx & 15;
    int ncol = ntv + col;
    int h = ncol >> 6, d = ncol & 63;
    short8 v = *(const short8*)&LT[col][tc * 8];
    *(short8*)&VT[((size_t)(b * 16 + h) * 64 + d) * 2048 + t0 + tc * 8] = v;
  }
}

// =====================================================================
// A: flash attention, SWAPPED pipeline: S^T = mfma(K,Q) so each lane owns
// one q-row (q = l&15) -> scalar m/l/alpha, in-lane softmax reduce + 2
// shfl_xor. O^T = mfma(V^T, P^T). K/V double-buffered, 1 barrier/tile.
// =====================================================================
__global__ __launch_bounds__(256) void attn_fwd(const ushort* __restrict__ Q,
                                                const ushort* __restrict__ Kb,
                                                const ushort* __restrict__ VT,
                                                ushort* __restrict__ Ohi,
                                                ushort* __restrict__ Olo){
  __shared__ __align__(16) ushort Ks[2][64 * 64];  // [key][d] swizzled
  __shared__ __align__(16) ushort Vs[2][64 * 64];  // [d][key] swizzled
  __shared__ __align__(16) ushort Ps[4][16][72];   // per-wave P^T [q][key]
  const int tid = threadIdx.x, w = tid >> 6, l = tid & 63;
  const int h = l >> 4, q = l & 15;                // lane's q-col / h-group
  const int bh = blockIdx.y, qbase = blockIdx.x * 64;
  const ushort* Qp = Q  + (size_t)bh * 2048 * 64;
  const ushort* Kp = Kb + (size_t)bh * 2048 * 64;
  const ushort* Vp = VT + (size_t)bh * 64 * 2048;  // [d][t]

  constexpr float DEFER_THR = 8.0f;                // 2^8 P-value headroom

  // Q as B-fragment: col = q (lane's row), k-slot = d
  const int qrow = qbase + w * 16 + q;
  short8 qf0 = *(const short8*)&Qp[(size_t)qrow * 64 + h * 8];
  short8 qf1 = *(const short8*)&Qp[(size_t)qrow * 64 + 32 + h * 8];

  float mrow = -1e30f, lrow = 0.f;
  f32x4 oacc[4];
  for (int c = 0; c < 4; ++c) for (int r = 0; r < 4; ++r) oacc[c][r] = 0.f;

  const int c0 = 2 * w, c1 = 2 * w + 1;
  // staging: inverse-swizzled source column (16B units): (l&7) ^ (l>>3)
  const int ssrc = ((l & 7) ^ (l >> 3)) * 8;
  const int sr0 = c0 * 8 + (l >> 3), sr1 = c1 * 8 + (l >> 3);
  // swizzled read col XOR (ushort units); fragment row within 16 = q
  const int rxor = (q & 7) * 8;

  // prologue stage tile 0 into buffer 0
  gload_lds16(Kp + (size_t)sr0 * 64 + ssrc, &Ks[0][c0 * 512]);
  gload_lds16(Kp + (size_t)sr1 * 64 + ssrc, &Ks[0][c1 * 512]);
  gload_lds16(Vp + (size_t)sr0 * 2048 + ssrc, &Vs[0][c0 * 512]);
  gload_lds16(Vp + (size_t)sr1 * 2048 + ssrc, &Vs[0][c1 * 512]);
  __syncthreads();

  int cur = 0;
  for (int kt = 0; kt < 32; ++kt){
    // issue next tile's loads into the other buffer (flies during compute)
    if (kt < 31){
      const int kb = (kt + 1) * 64;
      gload_lds16(Kp + (size_t)(kb + sr0) * 64 + ssrc, &Ks[cur ^ 1][c0 * 512]);
      gload_lds16(Kp + (size_t)(kb + sr1) * 64 + ssrc, &Ks[cur ^ 1][c1 * 512]);
      gload_lds16(Vp + (size_t)sr0 * 2048 + kb + ssrc, &Vs[cur ^ 1][c0 * 512]);
      gload_lds16(Vp + (size_t)sr1 * 2048 + kb + ssrc, &Vs[cur ^ 1][c1 * 512]);
    }
    const ushort* ks = Ks[cur];
    const ushort* vs = Vs[cur];

    // S^T = K·Q^T: A = K rows (key), B = Q cols (q). Lane: q fixed,
    // keys = 16nf + 4h + r across s[nf][r].
    f32x4 s[4];
    for (int nf = 0; nf < 4; ++nf) for (int r = 0; r < 4; ++r) s[nf][r] = 0.f;
    __builtin_amdgcn_s_setprio(1);
    for (int nf = 0; nf < 4; ++nf){
      int rb = (nf * 16 + q) * 64;
      short8 kf0 = *(const short8*)&ks[rb + ((h * 8)      ^ rxor)];
      short8 kf1 = *(const short8*)&ks[rb + ((h * 8 + 32) ^ rxor)];
      s[nf] = __builtin_amdgcn_mfma_f32_16x16x32_bf16(kf0, qf0, s[nf], 0, 0, 0);
      s[nf] = __builtin_amdgcn_mfma_f32_16x16x32_bf16(kf1, qf1, s[nf], 0, 0, 0);
    }
    __builtin_amdgcn_s_setprio(0);

    // row max: 15 in-lane + 2 cross-lane (quad {q, q+16, q+32, q+48})
    float pm01 = fmaxf(fmaxf(s[0][0], s[0][1]), fmaxf(s[0][2], s[0][3]));
    float pm23 = fmaxf(fmaxf(s[1][0], s[1][1]), fmaxf(s[1][2], s[1][3]));
    float pm45 = fmaxf(fmaxf(s[2][0], s[2][1]), fmaxf(s[2][2], s[2][3]));
    float pm67 = fmaxf(fmaxf(s[3][0], s[3][1]), fmaxf(s[3][2], s[3][3]));
    float pmax = fmaxf(fmaxf(pm01, pm23), fmaxf(pm45, pm67));
    pmax = fmaxf(pmax, __shfl_xor(pmax, 16));
    pmax = fmaxf(pmax, __shfl_xor(pmax, 32));

    // defer-max (T13): rescale only when the running max grew materially
    if (!__all(pmax <= mrow + DEFER_THR)){
      float mn = fmaxf(mrow, pmax);
      float alpha = __builtin_amdgcn_exp2f(mrow - mn);
      mrow = mn;
      lrow *= alpha;
      for (int c = 0; c < 4; ++c)
        for (int r = 0; r < 4; ++r) oacc[c][r] *= alpha;
    }

    // p = 2^(s - m), in-lane sum + 2 cross-lane
    float rsum = 0.f;
    for (int nf = 0; nf < 4; ++nf)
      for (int r = 0; r < 4; ++r){
        float p = __builtin_amdgcn_exp2f(s[nf][r] - mrow);
        s[nf][r] = p; rsum += p;
      }
    rsum += __shfl_xor(rsum, 16);
    rsum += __shfl_xor(rsum, 32);
    lrow += rsum;

    // P^T -> Ps[q][key] as 8 packed b32 writes (keys consecutive in pairs)
    for (int nf = 0; nf < 4; ++nf){
      unsigned pk01, pk23;
      asm("v_cvt_pk_bf16_f32 %0, %1, %2" : "=v"(pk01) : "v"(s[nf][0]), "v"(s[nf][1]));
      asm("v_cvt_pk_bf16_f32 %0, %1, %2" : "=v"(pk23) : "v"(s[nf][2]), "v"(s[nf][3]));
      int key = nf * 16 + 4 * h;
      *(unsigned*)&Ps[w][q][key]     = pk01;
      *(unsigned*)&Ps[w][q][key + 2] = pk23;
    }
    // no barrier: Ps is wave-private (lgkmcnt orders ds_write->ds_read)

    // O^T += V^T·P^T: A = V^T rows (d), B = P^T cols (q)
    __builtin_amdgcn_s_setprio(1);
    for (int st = 0; st < 2; ++st){
      short8 pf = *(const short8*)&Ps[w][q][st * 32 + h * 8];
      for (int c = 0; c < 4; ++c){
        int vb = (c * 16 + q) * 64;
        short8 vf = *(const short8*)&vs[vb + ((st * 32 + h * 8) ^ rxor)];
        oacc[c] = __builtin_amdgcn_mfma_f32_16x16x32_bf16(vf, pf, oacc[c], 0, 0, 0);
      }
    }
    __builtin_amdgcn_s_setprio(0);

    __syncthreads();   // new K/V landed (vmcnt0@barrier) + cur buffer free
    cur ^= 1;
  }

  // epilogue: lane owns q-row `qrow`, d = 16c + 4h + r (one head)
  const int b = bh >> 4, hh = bh & 15;
  float inv = 1.0f / lrow;
  size_t rowoff = ((size_t)(b * 2048 + qrow)) * 1024 + hh * 64;
  for (int c = 0; c < 4; ++c){
    int d0 = c * 16 + 4 * h;
    for (int pr = 0; pr < 2; ++pr){
      float v0 = oacc[c][2 * pr]     * inv;
      float v1 = oacc[c][2 * pr + 1] * inv;
      ushort h0 = f2bf(v0), h1 = f2bf(v1);
      unsigned hi = (unsigned)h0 | ((unsigned)h1 << 16);
      unsigned lo = (unsigned)f2bf(v0 - bf2f(h0)) | ((unsigned)f2bf(v1 - bf2f(h1)) << 16);
      *(unsigned*)&Ohi[rowoff + d0 + 2 * pr] = hi;
      *(unsigned*)&Olo[rowoff + d0 + 2 * pr] = lo;
    }
  }
}

// =====================================================================
// G2: output projection with bf16 hi/lo split (3 MFMAs per product)
// =====================================================================
__global__ __launch_bounds__(256) void gemm_out(const ushort* __restrict__ Ah,
                                                const ushort* __restrict__ Al,
                                                const ushort* __restrict__ BhT,
                                                const ushort* __restrict__ BlT,
                                                const float* __restrict__ bias,
                                                float* __restrict__ out){
  constexpr int K = 1024;
  __shared__ __align__(16) ushort Ash[128 * 32], Asl[128 * 32];
  __shared__ __align__(16) ushort Bsh[128 * 32], Bsl[128 * 32];
  const int tid = threadIdx.x, w = tid >> 6, l = tid & 63;
  const int wr = w >> 1, wc = w & 1;
  const int mtile = blockIdx.y * 128, ntile = blockIdx.x * 128;

  f32x4 acc[4][4];
  for (int m = 0; m < 4; ++m) for (int n = 0; n < 4; ++n)
    for (int r = 0; r < 4; ++r) acc[m][n][r] = 0.f;

  const int c0 = 2 * w, c1 = 2 * w + 1;
  const size_t aOff0 = (size_t)(mtile + c0 * 16 + (l >> 2)) * K + (l & 3) * 8;
  const size_t aOff1 = (size_t)(mtile + c1 * 16 + (l >> 2)) * K + (l & 3) * 8;
  const size_t bOff0 = (size_t)(ntile + c0 * 16 + (l >> 2)) * K + (l & 3) * 8;
  const size_t bOff1 = (size_t)(ntile + c1 * 16 + (l >> 2)) * K + (l & 3) * 8;

  for (int kt = 0; kt < K / 32; ++kt){
    __syncthreads();
    gload_lds16(Ah  + aOff0 + kt * 32, &Ash[c0 * 512]);
    gload_lds16(Ah  + aOff1 + kt * 32, &Ash[c1 * 512]);
    gload_lds16(Al  + aOff0 + kt * 32, &Asl[c0 * 512]);
    gload_lds16(Al  + aOff1 + kt * 32, &Asl[c1 * 512]);
    gload_lds16(BhT + bOff0 + kt * 32, &Bsh[c0 * 512]);
    gload_lds16(BhT + bOff1 + kt * 32, &Bsh[c1 * 512]);
    gload_lds16(BlT + bOff0 + kt * 32, &Bsl[c0 * 512]);
    gload_lds16(BlT + bOff1 + kt * 32, &Bsl[c1 * 512]);
    __syncthreads();
    short8 aH[4], aL[4], bH[4], bL[4];
    for (int m = 0; m < 4; ++m){
      int o = (wr * 64 + m * 16 + (l & 15)) * 32 + (l >> 4) * 8;
      aH[m] = *(const short8*)&Ash[o];
      aL[m] = *(const short8*)&Asl[o];
    }
    for (int n = 0; n < 4; ++n){
      int o = (wc * 64 + n * 16 + (l & 15)) * 32 + (l >> 4) * 8;
      bH[n] = *(const short8*)&Bsh[o];
      bL[n] = *(const short8*)&Bsl[o];
    }
    for (int m = 0; m < 4; ++m)
      for (int n = 0; n < 4; ++n){
        acc[m][n] = __builtin_amdgcn_mfma_f32_16x16x32_bf16(aH[m], bH[n], acc[m][n], 0, 0, 0);
        acc[m][n] = __builtin_amdgcn_mfma_f32_16x16x32_bf16(aH[m], bL[n], acc[m][n], 0, 0, 0);
        acc[m][n] = __builtin_amdgcn_mfma_f32_16x16x32_bf16(aL[m], bH[n], acc[m][n], 0, 0, 0);
      }
  }

  for (int nf = 0; nf < 4; ++nf){
    int ncol = ntile + wc * 64 + nf * 16 + (l & 15);
    float bv = bias[ncol];
    for (int m = 0; m < 4; ++m){
      int rbase = mtile + wr * 64 + m * 16 + (l >> 4) * 4;
      for (int r = 0; r < 4; ++r)
        out[(size_t)(rbase + r) * 1024 + ncol] = acc[m][nf][r] + bv;
    }
  }
}

// =====================================================================
extern "C" void kernel_launch(void* const* d_in, const int* in_sizes, int n_in,
                              void* d_out, int out_size, void* d_ws, size_t ws_size,
                              hipStream_t stream){
  const float* x     = (const float*)d_in[0];
  const float* w_qkv = (const float*)d_in[1];
  const float* b_qkv = (const float*)d_in[2];
  const float* w_out = (const float*)d_in[3];
  const float* b_out = (const float*)d_in[4];
  float* out = (float*)d_out;
  char* ws = (char*)d_ws;

  size_t off = 0;
  auto alloc = [&](size_t bytes){ size_t o = off; off += (bytes + 255) & ~(size_t)255; return o; };
  const size_t SZ_X   = (size_t)8192 * 1024 * 2;   // 16 MiB
  const size_t SZ_QKV = (size_t)64 * 2048 * 64 * 2;
  size_t o_xb  = alloc(SZ_X);                      // xb; reused as Ohi after G1
  size_t o_wq  = alloc((size_t)3072 * 1024 * 2);
  size_t o_q   = alloc(SZ_QKV);
  size_t o_k   = alloc(SZ_QKV);
  size_t o_v   = alloc(SZ_QKV);                    // VT[bh][d][t]
  size_t o_olo = alloc(SZ_X);
  size_t o_wh  = alloc((size_t)1024 * 1024 * 2);
  size_t o_wl  = alloc((size_t)1024 * 1024 * 2);

  ushort* xb  = (ushort*)(ws + o_xb);
  ushort* wqT = (ushort*)(ws + o_wq);
  ushort* Qb  = (ushort*)(ws + o_q);
  ushort* Kb  = (ushort*)(ws + o_k);
  ushort* VTb = (ushort*)(ws + o_v);
  ushort* Ohi = (ushort*)(ws + o_xb);              // alias: xb dead after G1
  ushort* Olo = (ushort*)(ws + o_olo);
  ushort* WhT = (ushort*)(ws + o_wh);
  ushort* WlT = (ushort*)(ws + o_wl);

  cast_bf16<<<8192, 256, 0, stream>>>((const float4*)x, xb, 8192 * 1024 / 4);
  transpose_cast<0><<<dim3(48, 16), 256, 0, stream>>>(w_qkv, wqT, nullptr, 1024, 3072);
  transpose_cast<1><<<dim3(16, 16), 256, 0, stream>>>(w_out, WhT, WlT, 1024, 1024);
  gemm_qk<<<dim3(16, 64), 256, 0, stream>>>(xb, wqT, b_qkv, Qb, Kb);
  gemm_vT<<<dim3(8, 64), 256, 0, stream>>>(xb, wqT, b_qkv, VTb);
  attn_fwd<<<dim3(32, 64), 256, 0, stream>>>(Qb, Kb, VTb, Ohi, Olo);
  gemm_out<<<dim3(8, 64), 256, 0, stream>>>(Ohi, Olo, WhT, WlT, b_out, out);
}

// Round 12
// 339.374 us; speedup vs baseline: 1.4221x; 1.0863x over previous
//
#include <hip/hip_runtime.h>
#include <hip/hip_bf16.h>

typedef __attribute__((ext_vector_type(8))) short short8;
typedef __attribute__((ext_vector_type(4))) float f32x4;
typedef __attribute__((ext_vector_type(4))) unsigned short ushort4v;
typedef unsigned short ushort;

#define DEVI static __device__ __forceinline__

// ---------- bf16 helpers (RNE) ----------
DEVI ushort f2bf(float f){
  union { float f; unsigned u; } v; v.f = f;
  unsigned r = v.u + 0x7fffu + ((v.u >> 16) & 1u);
  return (ushort)(r >> 16);
}
DEVI float bf2f(ushort u){
  union { unsigned u; float f; } v; v.u = ((unsigned)u) << 16;
  return v.f;
}

// ---------- async global->LDS (16B per lane, linear dest) ----------
DEVI void gload_lds16(const void* g, void* l){
  __builtin_amdgcn_global_load_lds(
      (const __attribute__((address_space(1))) void*)g,
      (__attribute__((address_space(3))) void*)l, 16, 0, 0);
}

// =====================================================================
// P1: cast fp32 -> bf16 (vectorized)
// =====================================================================
__global__ __launch_bounds__(256) void cast_bf16(const float4* __restrict__ in,
                                                 ushort* __restrict__ out, int n4){
  int i = blockIdx.x * 256 + threadIdx.x;
  if (i < n4){
    float4 v = in[i];
    ushort4v o = { f2bf(v.x), f2bf(v.y), f2bf(v.z), f2bf(v.w) };
    *(ushort4v*)&out[(size_t)i * 4] = o;
  }
}

// =====================================================================
// P2: transpose + cast fp32[R][C] -> bf16[C][R] (optional hi/lo split)
// =====================================================================
template<int SPLIT>
__global__ __launch_bounds__(256) void transpose_cast(const float* __restrict__ in,
                                                      ushort* __restrict__ outT,
                                                      ushort* __restrict__ outLo,
                                                      int R, int C){
  __shared__ float tile[64][65];
  const int r0 = blockIdx.y * 64, c0 = blockIdx.x * 64;
  const int t = threadIdx.x;
  for (int it = 0; it < 16; ++it){
    int idx = it * 256 + t; int rr = idx >> 6, cc = idx & 63;
    tile[rr][cc] = in[(size_t)(r0 + rr) * C + (c0 + cc)];
  }
  __syncthreads();
  for (int it = 0; it < 16; ++it){
    int idx = it * 256 + t; int oc = idx >> 6, orow = idx & 63;
    float v = tile[orow][oc];
    ushort hi = f2bf(v);
    size_t o = (size_t)(c0 + oc) * R + (r0 + orow);
    outT[o] = hi;
    if (SPLIT) outLo[o] = f2bf(v - bf2f(hi));
  }
}

// =====================================================================
// G1a: Q/K projection (cols 0..2047).  Q is pre-scaled by 0.125*log2(e)
// so the attention softmax runs in the exp2 domain with no per-score mul.
// =====================================================================
__global__ __launch_bounds__(256) void gemm_qk(const ushort* __restrict__ A,
                                               const ushort* __restrict__ BT,
                                               const float* __restrict__ bias,
                                               ushort* __restrict__ Qo,
                                               ushort* __restrict__ Ko){
  constexpr int K = 1024;
  constexpr float QSCALE = 0.18033688011112042f;   // 0.125 * log2(e)
  __shared__ __align__(16) ushort As[128 * 32];
  __shared__ __align__(16) ushort Bs[128 * 32];
  const int tid = threadIdx.x, w = tid >> 6, l = tid & 63;
  const int wr = w >> 1, wc = w & 1;
  const int mtile = blockIdx.y * 128, ntile = blockIdx.x * 128;

  f32x4 acc[4][4];
  for (int m = 0; m < 4; ++m) for (int n = 0; n < 4; ++n)
    for (int r = 0; r < 4; ++r) acc[m][n][r] = 0.f;

  const int c0 = 2 * w, c1 = 2 * w + 1;
  const ushort* aG0 = A  + (size_t)(mtile + c0 * 16 + (l >> 2)) * K + (l & 3) * 8;
  const ushort* aG1 = A  + (size_t)(mtile + c1 * 16 + (l >> 2)) * K + (l & 3) * 8;
  const ushort* bG0 = BT + (size_t)(ntile + c0 * 16 + (l >> 2)) * K + (l & 3) * 8;
  const ushort* bG1 = BT + (size_t)(ntile + c1 * 16 + (l >> 2)) * K + (l & 3) * 8;

  for (int kt = 0; kt < K / 32; ++kt){
    __syncthreads();
    gload_lds16(aG0 + kt * 32, &As[c0 * 512]);
    gload_lds16(aG1 + kt * 32, &As[c1 * 512]);
    gload_lds16(bG0 + kt * 32, &Bs[c0 * 512]);
    gload_lds16(bG1 + kt * 32, &Bs[c1 * 512]);
    __syncthreads();
    short8 aF[4], bF[4];
    for (int m = 0; m < 4; ++m)
      aF[m] = *(const short8*)&As[(wr * 64 + m * 16 + (l & 15)) * 32 + (l >> 4) * 8];
    for (int n = 0; n < 4; ++n)
      bF[n] = *(const short8*)&Bs[(wc * 64 + n * 16 + (l & 15)) * 32 + (l >> 4) * 8];
    for (int m = 0; m < 4; ++m)
      for (int n = 0; n < 4; ++n)
        acc[m][n] = __builtin_amdgcn_mfma_f32_16x16x32_bf16(aF[m], bF[n], acc[m][n], 0, 0, 0);
  }

  for (int nf = 0; nf < 4; ++nf){
    int ncol = ntile + wc * 64 + nf * 16 + (l & 15);
    float bv = bias[ncol];
    int isQ = (ncol < 1024) ? 1 : 0;
    int h = (ncol >> 6) & 15, d = ncol & 63;
    ushort* dst = isQ ? Qo : Ko;
    float sc = isQ ? QSCALE : 1.0f;
    for (int m = 0; m < 4; ++m){
      int rbase = mtile + wr * 64 + m * 16 + (l >> 4) * 4;
      for (int r = 0; r < 4; ++r){
        int row = rbase + r;
        int b = row >> 11, t = row & 2047;
        dst[((size_t)(b * 16 + h) * 2048 + t) * 64 + d] = f2bf((acc[m][nf][r] + bv) * sc);
      }
    }
  }
}

// =====================================================================
// G1b: V projection (cols 2048..3071) writing V TRANSPOSED:
// VT[bh][d][t] — so attention can stage V via global_load_lds like K.
// =====================================================================
__global__ __launch_bounds__(256) void gemm_vT(const ushort* __restrict__ A,
                                               const ushort* __restrict__ BT,
                                               const float* __restrict__ bias,
                                               ushort* __restrict__ VT){
  constexpr int K = 1024;
  __shared__ __align__(16) ushort As[128 * 32];
  __shared__ __align__(16) ushort Bs[128 * 32];
  __shared__ __align__(16) ushort LT[128][136];    // [col][t], 16B-aligned rows
  const int tid = threadIdx.x, w = tid >> 6, l = tid & 63;
  const int wr = w >> 1, wc = w & 1;
  const int mtile = blockIdx.y * 128, ntv = blockIdx.x * 128;  // ntv in 0..1023

  f32x4 acc[4][4];
  for (int m = 0; m < 4; ++m) for (int n = 0; n < 4; ++n)
    for (int r = 0; r < 4; ++r) acc[m][n][r] = 0.f;

  const int c0 = 2 * w, c1 = 2 * w + 1;
  const ushort* aG0 = A  + (size_t)(mtile + c0 * 16 + (l >> 2)) * K + (l & 3) * 8;
  const ushort* aG1 = A  + (size_t)(mtile + c1 * 16 + (l >> 2)) * K + (l & 3) * 8;
  const ushort* bG0 = BT + (size_t)(2048 + ntv + c0 * 16 + (l >> 2)) * K + (l & 3) * 8;
  const ushort* bG1 = BT + (size_t)(2048 + ntv + c1 * 16 + (l >> 2)) * K + (l & 3) * 8;

  for (int kt = 0; kt < K / 32; ++kt){
    __syncthreads();
    gload_lds16(aG0 + kt * 32, &As[c0 * 512]);
    gload_lds16(aG1 + kt * 32, &As[c1 * 512]);
    gload_lds16(bG0 + kt * 32, &Bs[c0 * 512]);
    gload_lds16(bG1 + kt * 32, &Bs[c1 * 512]);
    __syncthreads();
    short8 aF[4], bF[4];
    for (int m = 0; m < 4; ++m)
      aF[m] = *(const short8*)&As[(wr * 64 + m * 16 + (l & 15)) * 32 + (l >> 4) * 8];
    for (int n = 0; n < 4; ++n)
      bF[n] = *(const short8*)&Bs[(wc * 64 + n * 16 + (l & 15)) * 32 + (l >> 4) * 8];
    for (int m = 0; m < 4; ++m)
      for (int n = 0; n < 4; ++n)
        acc[m][n] = __builtin_amdgcn_mfma_f32_16x16x32_bf16(aF[m], bF[n], acc[m][n], 0, 0, 0);
  }

  // epilogue: acc -> LT[col][t_local], then coalesced VT[bh][d][t] writes
  for (int nf = 0; nf < 4; ++nf){
    int cl = wc * 64 + nf * 16 + (l & 15);
    float bv = bias[2048 + ntv + cl];
    for (int m = 0; m < 4; ++m){
      int rl = wr * 64 + m * 16 + (l >> 4) * 4;
      for (int r = 0; r < 4; ++r)
        LT[cl][rl + r] = f2bf(acc[m][nf][r] + bv);
    }
  }
  __syncthreads();
  const int b = mtile >> 11, t0 = mtile & 2047;
  for (int p = 0; p < 8; ++p){
    int idx = p * 256 + tid;
    int col = idx >> 4, tc = idx & 15;
    int ncol = ntv + col;
    int h = ncol >> 6, d = ncol & 63;
    short8 v = *(const short8*)&LT[col][tc * 8];
    *(short8*)&VT[((size_t)(b * 16 + h) * 64 + d) * 2048 + t0 + tc * 8] = v;
  }
}

// =====================================================================
// A: flash attention, swapped pipeline, 8 waves x 16 q-rows = QBLK 128.
// One K/V stage feeds 128 q-rows (2x arithmetic intensity vs QBLK 64).
// XCD-aware block remap: each XCD owns 8 bh -> K/V stays in its L2.
// =====================================================================
__global__ __launch_bounds__(512) void attn_fwd(const ushort* __restrict__ Q,
                                                const ushort* __restrict__ Kb,
                                                const ushort* __restrict__ VT,
                                                ushort* __restrict__ Ohi,
                                                ushort* __restrict__ Olo){
  __shared__ __align__(16) ushort Ks[2][64 * 64];  // [key][d] swizzled
  __shared__ __align__(16) ushort Vs[2][64 * 64];  // [d][key] swizzled
  __shared__ __align__(16) ushort Ps[8][16][72];   // per-wave P^T [q][key]
  const int tid = threadIdx.x, w = tid >> 6, l = tid & 63;
  const int h = l >> 4, q = l & 15;                // lane's q-col / h-group

  // XCD-aware remap: grid (16,64); assume xcd = linear_id % 8.
  // Each XCD owns bh in [8*xcd, 8*xcd+8) -> K/V working set ~3MB fits L2.
  const int id = blockIdx.y * 16 + blockIdx.x;
  const int xcd = id & 7, idx = id >> 3;           // idx 0..127
  const int bh = xcd * 8 + (idx >> 4);
  const int qbase = (idx & 15) * 128;

  const ushort* Qp = Q  + (size_t)bh * 2048 * 64;
  const ushort* Kp = Kb + (size_t)bh * 2048 * 64;
  const ushort* Vp = VT + (size_t)bh * 64 * 2048;  // [d][t]

  constexpr float DEFER_THR = 8.0f;                // 2^8 P-value headroom

  // Q as B-fragment: col = q (lane's row), k-slot = d
  const int qrow = qbase + w * 16 + q;
  short8 qf0 = *(const short8*)&Qp[(size_t)qrow * 64 + h * 8];
  short8 qf1 = *(const short8*)&Qp[(size_t)qrow * 64 + 32 + h * 8];

  float mrow = -1e30f, lrow = 0.f;
  f32x4 oacc[4];
  for (int c = 0; c < 4; ++c) for (int r = 0; r < 4; ++r) oacc[c][r] = 0.f;

  // staging: wave w covers rows [8w, 8w+8); lane row = 8w + (l>>3)
  // inverse-swizzled source column (16B units): (l&7) ^ (l>>3)
  const int ssrc = ((l & 7) ^ (l >> 3)) * 8;
  const int srow = w * 8 + (l >> 3);
  // swizzled read col XOR (ushort units); fragment row within 16 = q
  const int rxor = (q & 7) * 8;

  // prologue stage tile 0 into buffer 0 (1 K-load + 1 V-load per wave)
  gload_lds16(Kp + (size_t)srow * 64 + ssrc, &Ks[0][w * 512]);
  gload_lds16(Vp + (size_t)srow * 2048 + ssrc, &Vs[0][w * 512]);
  __syncthreads();

  int cur = 0;
  for (int kt = 0; kt < 32; ++kt){
    // issue next tile's loads into the other buffer (flies during compute)
    if (kt < 31){
      const int kb = (kt + 1) * 64;
      gload_lds16(Kp + (size_t)(kb + srow) * 64 + ssrc, &Ks[cur ^ 1][w * 512]);
      gload_lds16(Vp + (size_t)srow * 2048 + kb + ssrc, &Vs[cur ^ 1][w * 512]);
    }
    const ushort* ks = Ks[cur];
    const ushort* vs = Vs[cur];

    // S^T = K·Q^T: A = K rows (key), B = Q cols (q). Lane: q fixed,
    // keys = 16nf + 4h + r across s[nf][r].
    f32x4 s[4];
    for (int nf = 0; nf < 4; ++nf) for (int r = 0; r < 4; ++r) s[nf][r] = 0.f;
    __builtin_amdgcn_s_setprio(1);
    for (int nf = 0; nf < 4; ++nf){
      int rb = (nf * 16 + q) * 64;
      short8 kf0 = *(const short8*)&ks[rb + ((h * 8)      ^ rxor)];
      short8 kf1 = *(const short8*)&ks[rb + ((h * 8 + 32) ^ rxor)];
      s[nf] = __builtin_amdgcn_mfma_f32_16x16x32_bf16(kf0, qf0, s[nf], 0, 0, 0);
      s[nf] = __builtin_amdgcn_mfma_f32_16x16x32_bf16(kf1, qf1, s[nf], 0, 0, 0);
    }
    __builtin_amdgcn_s_setprio(0);

    // row max: max3-friendly chains (2 parallel) + 2 cross-lane
    float ma = fmaxf(fmaxf(s[0][0], s[0][1]), s[0][2]);
    ma = fmaxf(fmaxf(ma, s[0][3]), s[1][0]);
    ma = fmaxf(fmaxf(ma, s[1][1]), s[1][2]);
    float mb = fmaxf(fmaxf(s[1][3], s[2][0]), s[2][1]);
    mb = fmaxf(fmaxf(mb, s[2][2]), s[2][3]);
    mb = fmaxf(fmaxf(mb, s[3][0]), s[3][1]);
    float pmax = fmaxf(fmaxf(ma, mb), fmaxf(s[3][2], s[3][3]));
    pmax = fmaxf(pmax, __shfl_xor(pmax, 16));
    pmax = fmaxf(pmax, __shfl_xor(pmax, 32));

    // defer-max (T13): rescale only when the running max grew materially
    if (!__all(pmax <= mrow + DEFER_THR)){
      float mn = fmaxf(mrow, pmax);
      float alpha = __builtin_amdgcn_exp2f(mrow - mn);
      mrow = mn;
      lrow *= alpha;
      for (int c = 0; c < 4; ++c)
        for (int r = 0; r < 4; ++r) oacc[c][r] *= alpha;
    }

    // p = 2^(s - m), in-lane sum + 2 cross-lane
    float rsum = 0.f;
    for (int nf = 0; nf < 4; ++nf)
      for (int r = 0; r < 4; ++r){
        float p = __builtin_amdgcn_exp2f(s[nf][r] - mrow);
        s[nf][r] = p; rsum += p;
      }
    rsum += __shfl_xor(rsum, 16);
    rsum += __shfl_xor(rsum, 32);
    lrow += rsum;

    // P^T -> Ps[q][key] as 8 packed b32 writes (keys consecutive in pairs)
    for (int nf = 0; nf < 4; ++nf){
      unsigned pk01, pk23;
      asm("v_cvt_pk_bf16_f32 %0, %1, %2" : "=v"(pk01) : "v"(s[nf][0]), "v"(s[nf][1]));
      asm("v_cvt_pk_bf16_f32 %0, %1, %2" : "=v"(pk23) : "v"(s[nf][2]), "v"(s[nf][3]));
      int key = nf * 16 + 4 * h;
      *(unsigned*)&Ps[w][q][key]     = pk01;
      *(unsigned*)&Ps[w][q][key + 2] = pk23;
    }
    // no barrier: Ps is wave-private (lgkmcnt orders ds_write->ds_read)

    // O^T += V^T·P^T: A = V^T rows (d), B = P^T cols (q)
    __builtin_amdgcn_s_setprio(1);
    for (int st = 0; st < 2; ++st){
      short8 pf = *(const short8*)&Ps[w][q][st * 32 + h * 8];
      for (int c = 0; c < 4; ++c){
        int vb = (c * 16 + q) * 64;
        short8 vf = *(const short8*)&vs[vb + ((st * 32 + h * 8) ^ rxor)];
        oacc[c] = __builtin_amdgcn_mfma_f32_16x16x32_bf16(vf, pf, oacc[c], 0, 0, 0);
      }
    }
    __builtin_amdgcn_s_setprio(0);

    __syncthreads();   // new K/V landed (vmcnt0@barrier) + cur buffer free
    cur ^= 1;
  }

  // epilogue: lane owns q-row `qrow`, d = 16c + 4h + r (one head)
  const int b = bh >> 4, hh = bh & 15;
  float inv = 1.0f / lrow;
  size_t rowoff = ((size_t)(b * 2048 + qrow)) * 1024 + hh * 64;
  for (int c = 0; c < 4; ++c){
    int d0 = c * 16 + 4 * h;
    for (int pr = 0; pr < 2; ++pr){
      float v0 = oacc[c][2 * pr]     * inv;
      float v1 = oacc[c][2 * pr + 1] * inv;
      ushort h0 = f2bf(v0), h1 = f2bf(v1);
      unsigned hi = (unsigned)h0 | ((unsigned)h1 << 16);
      unsigned lo = (unsigned)f2bf(v0 - bf2f(h0)) | ((unsigned)f2bf(v1 - bf2f(h1)) << 16);
      *(unsigned*)&Ohi[rowoff + d0 + 2 * pr] = hi;
      *(unsigned*)&Olo[rowoff + d0 + 2 * pr] = lo;
    }
  }
}

// =====================================================================
// G2: output projection with bf16 hi/lo split (3 MFMAs per product)
// =====================================================================
__global__ __launch_bounds__(256) void gemm_out(const ushort* __restrict__ Ah,
                                                const ushort* __restrict__ Al,
                                                const ushort* __restrict__ BhT,
                                                const ushort* __restrict__ BlT,
                                                const float* __restrict__ bias,
                                                float* __restrict__ out){
  constexpr int K = 1024;
  __shared__ __align__(16) ushort Ash[128 * 32], Asl[128 * 32];
  __shared__ __align__(16) ushort Bsh[128 * 32], Bsl[128 * 32];
  const int tid = threadIdx.x, w = tid >> 6, l = tid & 63;
  const int wr = w >> 1, wc = w & 1;
  const int mtile = blockIdx.y * 128, ntile = blockIdx.x * 128;

  f32x4 acc[4][4];
  for (int m = 0; m < 4; ++m) for (int n = 0; n < 4; ++n)
    for (int r = 0; r < 4; ++r) acc[m][n][r] = 0.f;

  const int c0 = 2 * w, c1 = 2 * w + 1;
  const size_t aOff0 = (size_t)(mtile + c0 * 16 + (l >> 2)) * K + (l & 3) * 8;
  const size_t aOff1 = (size_t)(mtile + c1 * 16 + (l >> 2)) * K + (l & 3) * 8;
  const size_t bOff0 = (size_t)(ntile + c0 * 16 + (l >> 2)) * K + (l & 3) * 8;
  const size_t bOff1 = (size_t)(ntile + c1 * 16 + (l >> 2)) * K + (l & 3) * 8;

  for (int kt = 0; kt < K / 32; ++kt){
    __syncthreads();
    gload_lds16(Ah  + aOff0 + kt * 32, &Ash[c0 * 512]);
    gload_lds16(Ah  + aOff1 + kt * 32, &Ash[c1 * 512]);
    gload_lds16(Al  + aOff0 + kt * 32, &Asl[c0 * 512]);
    gload_lds16(Al  + aOff1 + kt * 32, &Asl[c1 * 512]);
    gload_lds16(BhT + bOff0 + kt * 32, &Bsh[c0 * 512]);
    gload_lds16(BhT + bOff1 + kt * 32, &Bsh[c1 * 512]);
    gload_lds16(BlT + bOff0 + kt * 32, &Bsl[c0 * 512]);
    gload_lds16(BlT + bOff1 + kt * 32, &Bsl[c1 * 512]);
    __syncthreads();
    short8 aH[4], aL[4], bH[4], bL[4];
    for (int m = 0; m < 4; ++m){
      int o = (wr * 64 + m * 16 + (l & 15)) * 32 + (l >> 4) * 8;
      aH[m] = *(const short8*)&Ash[o];
      aL[m] = *(const short8*)&Asl[o];
    }
    for (int n = 0; n < 4; ++n){
      int o = (wc * 64 + n * 16 + (l & 15)) * 32 + (l >> 4) * 8;
      bH[n] = *(const short8*)&Bsh[o];
      bL[n] = *(const short8*)&Bsl[o];
    }
    for (int m = 0; m < 4; ++m)
      for (int n = 0; n < 4; ++n){
        acc[m][n] = __builtin_amdgcn_mfma_f32_16x16x32_bf16(aH[m], bH[n], acc[m][n], 0, 0, 0);
        acc[m][n] = __builtin_amdgcn_mfma_f32_16x16x32_bf16(aH[m], bL[n], acc[m][n], 0, 0, 0);
        acc[m][n] = __builtin_amdgcn_mfma_f32_16x16x32_bf16(aL[m], bH[n], acc[m][n], 0, 0, 0);
      }
  }

  for (int nf = 0; nf < 4; ++nf){
    int ncol = ntile + wc * 64 + nf * 16 + (l & 15);
    float bv = bias[ncol];
    for (int m = 0; m < 4; ++m){
      int rbase = mtile + wr * 64 + m * 16 + (l >> 4) * 4;
      for (int r = 0; r < 4; ++r)
        out[(size_t)(rbase + r) * 1024 + ncol] = acc[m][nf][r] + bv;
    }
  }
}

// =====================================================================
extern "C" void kernel_launch(void* const* d_in, const int* in_sizes, int n_in,
                              void* d_out, int out_size, void* d_ws, size_t ws_size,
                              hipStream_t stream){
  const float* x     = (const float*)d_in[0];
  const float* w_qkv = (const float*)d_in[1];
  const float* b_qkv = (const float*)d_in[2];
  const float* w_out = (const float*)d_in[3];
  const float* b_out = (const float*)d_in[4];
  float* out = (float*)d_out;
  char* ws = (char*)d_ws;

  size_t off = 0;
  auto alloc = [&](size_t bytes){ size_t o = off; off += (bytes + 255) & ~(size_t)255; return o; };
  const size_t SZ_X   = (size_t)8192 * 1024 * 2;   // 16 MiB
  const size_t SZ_QKV = (size_t)64 * 2048 * 64 * 2;
  size_t o_xb  = alloc(SZ_X);                      // xb; reused as Ohi after G1
  size_t o_wq  = alloc((size_t)3072 * 1024 * 2);
  size_t o_q   = alloc(SZ_QKV);
  size_t o_k   = alloc(SZ_QKV);
  size_t o_v   = alloc(SZ_QKV);                    // VT[bh][d][t]
  size_t o_olo = alloc(SZ_X);
  size_t o_wh  = alloc((size_t)1024 * 1024 * 2);
  size_t o_wl  = alloc((size_t)1024 * 1024 * 2);

  ushort* xb  = (ushort*)(ws + o_xb);
  ushort* wqT = (ushort*)(ws + o_wq);
  ushort* Qb  = (ushort*)(ws + o_q);
  ushort* Kb  = (ushort*)(ws + o_k);
  ushort* VTb = (ushort*)(ws + o_v);
  ushort* Ohi = (ushort*)(ws + o_xb);              // alias: xb dead after G1
  ushort* Olo = (ushort*)(ws + o_olo);
  ushort* WhT = (ushort*)(ws + o_wh);
  ushort* WlT = (ushort*)(ws + o_wl);

  cast_bf16<<<8192, 256, 0, stream>>>((const float4*)x, xb, 8192 * 1024 / 4);
  transpose_cast<0><<<dim3(48, 16), 256, 0, stream>>>(w_qkv, wqT, nullptr, 1024, 3072);
  transpose_cast<1><<<dim3(16, 16), 256, 0, stream>>>(w_out, WhT, WlT, 1024, 1024);
  gemm_qk<<<dim3(16, 64), 256, 0, stream>>>(xb, wqT, b_qkv, Qb, Kb);
  gemm_vT<<<dim3(8, 64), 256, 0, stream>>>(xb, wqT, b_qkv, VTb);
  attn_fwd<<<dim3(16, 64), 512, 0, stream>>>(Qb, Kb, VTb, Ohi, Olo);
  gemm_out<<<dim3(8, 64), 256, 0, stream>>>(Ohi, Olo, WhT, WlT, b_out, out);
}